// Round 16
// baseline (563.170 us; speedup 1.0000x reference)
//
#include <hip/hip_runtime.h>

#define NN 50000
#define NE 800000
#define NIN 32
#define EIN 16
#define HID 128
#define NL 3
#define NG 256
#define TE 64
#define BM 64        // kMlp row tile
#define SCAN_B 196   // ceil(NN/256)
#define NB_AGG 3125  // kAgg blocks (x4 waves = 12500 waves, exactly 4 nodes/wave)

typedef unsigned short ushort_t;
typedef __attribute__((ext_vector_type(8))) _Float16 half8;
typedef __attribute__((ext_vector_type(4))) float f32x4;
typedef __attribute__((ext_vector_type(2))) __fp16 h2;

__device__ __forceinline__ unsigned pkf16(float a, float b){
  h2 h = __builtin_amdgcn_cvt_pkrtz(a, b);
  union{ h2 h; unsigned u; } c; c.h = h; return c.u;
}
__device__ __forceinline__ h2 u2h(unsigned u){
  union{ unsigned u; h2 h; } c; c.u = u; return c.h;
}
__device__ __forceinline__ unsigned h2u(h2 h){
  union{ h2 h; unsigned u; } c; c.h = h; return c.u;
}
__device__ __forceinline__ ushort_t f2h(float x){
  union{ __fp16 h; ushort_t u; } c; c.h = (__fp16)x; return c.u;
}
__device__ __forceinline__ float h2f(ushort_t v){
  union{ ushort_t u; __fp16 h; } c; c.u = v; return (float)c.h;
}

// v_pk_fma_f16 with op_sel broadcast of src0 half (zero-cost scalar splat)
#define PKFMA_LO(a, e, w) asm("v_pk_fma_f16 %0, %1, %2, %0 op_sel:[0,0,0] op_sel_hi:[0,1,1]" : "+v"(a) : "v"(e), "v"(w))
#define PKFMA_HI(a, e, w) asm("v_pk_fma_f16 %0, %1, %2, %0 op_sel:[1,0,0] op_sel_hi:[1,1,1]" : "+v"(a) : "v"(e), "v"(w))
// acc(f32) += f16 half of t (single instruction f16->f32 accumulate)
#define FMAMIX_LO(acc, t, one) asm("v_fma_mix_f32 %0, %1, %2, %0 op_sel:[0,0,0] op_sel_hi:[1,0,0]" : "+v"(acc) : "v"(t), "v"(one))
#define FMAMIX_HI(acc, t, one) asm("v_fma_mix_f32 %0, %1, %2, %0 op_sel:[1,0,0] op_sel_hi:[1,0,0]" : "+v"(acc) : "v"(t), "v"(one))

typedef const __attribute__((address_space(1))) unsigned gas_t;
typedef __attribute__((address_space(3))) unsigned las_t;
__device__ __forceinline__ void stage16(const void* g, void* l){
  __builtin_amdgcn_global_load_lds((gas_t*)g, (las_t*)l, 16, 0, 0);
}

// ======================= CSR build (dst-sorted) =======================
__global__ void kHist(const int* __restrict__ dst, int* __restrict__ cnt){
  int e = blockIdx.x*256 + threadIdx.x;
  if (e < NE) atomicAdd(&cnt[dst[e]], 1);
}

__global__ void kPartSum(const int* __restrict__ cnt, int* __restrict__ psum){
  __shared__ int sm[256];
  int b = blockIdx.x, t = threadIdx.x, i = b*256 + t;
  sm[t] = (i < NN) ? cnt[i] : 0;
  __syncthreads();
  for (int o = 128; o > 0; o >>= 1){
    if (t < o) sm[t] += sm[t + o];
    __syncthreads();
  }
  if (t == 0) psum[b] = sm[0];
}

__global__ __launch_bounds__(256) void kScanPart(const int* __restrict__ psum,
                                                 int* __restrict__ pofs, int* __restrict__ offs){
  __shared__ int sm[256];
  int t = threadIdx.x;
  int v = (t < SCAN_B) ? psum[t] : 0;
  sm[t] = v;
  __syncthreads();
  for (int o = 1; o < 256; o <<= 1){
    int x = (t >= o) ? sm[t - o] : 0;
    __syncthreads();
    sm[t] += x;
    __syncthreads();
  }
  if (t < SCAN_B) pofs[t] = sm[t] - v;
  if (t == 255) offs[NN] = sm[255];
}

__global__ void kScanApply(const int* __restrict__ cnt, const int* __restrict__ pofs,
                           int* __restrict__ offs, int* __restrict__ curs){
  __shared__ int sm[256];
  int b = blockIdx.x, t = threadIdx.x, i = b*256 + t;
  int v = (i < NN) ? cnt[i] : 0;
  sm[t] = v;
  __syncthreads();
  for (int o = 1; o < 256; o <<= 1){
    int x = (t >= o) ? sm[t - o] : 0;
    __syncthreads();
    sm[t] += x;
    __syncthreads();
  }
  int ex = sm[t] - v + pofs[b];
  if (i < NN){ offs[i] = ex; curs[i] = ex; }
}

// scatter only the permutation (4B) — minimal scattered-write footprint
__global__ void kScatterPerm(const int* __restrict__ dst, int* __restrict__ curs,
                             int* __restrict__ perm){
  int e = blockIdx.x*256 + threadIdx.x;
  if (e < NE){
    int p = atomicAdd(&curs[dst[e]], 1);
    perm[p] = e;
  }
}

// gather side: coalesced over CSR positions; eattr rows are 64B-aligned full sectors
__global__ void kGatherEA(const int* __restrict__ perm, const int* __restrict__ src,
                          const float* __restrict__ eattr,
                          int* __restrict__ srcPos, unsigned* __restrict__ eaPos){
  int p = blockIdx.x*256 + threadIdx.x;
  if (p >= NE) return;
  int e = perm[p];
  srcPos[p] = src[e];
  const float4* row = (const float4*)(eattr + (size_t)e*EIN);
  float4 v0 = row[0], v1 = row[1], v2 = row[2], v3 = row[3];
  uint4 d0, d1;
  d0.x = pkf16(v0.x, v0.y); d0.y = pkf16(v0.z, v0.w);
  d0.z = pkf16(v1.x, v1.y); d0.w = pkf16(v1.z, v1.w);
  d1.x = pkf16(v2.x, v2.y); d1.y = pkf16(v2.z, v2.w);
  d1.z = pkf16(v3.x, v3.y); d1.w = pkf16(v3.z, v3.w);
  *(uint4*)&eaPos[(size_t)p*8]     = d0;
  *(uint4*)&eaPos[(size_t)p*8 + 4] = d1;
}

// ======================= W -> f16 conversions + cnt zeroing (fused) =======================
__global__ void kConvW(const float* __restrict__ w1, const float* __restrict__ w2,
                       const float* __restrict__ nw,
                       ushort_t* __restrict__ wtb, ushort_t* __restrict__ wemb2,
                       int* __restrict__ cnt){
  int gid = blockIdx.x*256 + threadIdx.x;
  if (gid < 6*16384){
    int mat = gid >> 14, idx = gid & 16383;
    int k = idx >> 7, n = idx & 127;
    const float* src = (mat < 3) ? (w1 + (size_t)mat*16384) : (w2 + (size_t)(mat-3)*16384);
    wtb[(size_t)mat*16384 + n*128 + (k ^ ((n&7)<<3))] = f2h(src[idx]);
  } else if (gid < 6*16384 + NIN*HID){
    int i = gid - 6*16384;
    wemb2[i] = f2h(nw[i]);
  } else {
    int i = gid - (6*16384 + NIN*HID);
    if (i < NN) cnt[i] = 0;
  }
}

// ======================= node embed -> hf (f16), LDS-staged =======================
__global__ __launch_bounds__(256) void kNodeInit2(const float* __restrict__ x,
    const ushort_t* __restrict__ wemb2, const float* __restrict__ b,
    ushort_t* __restrict__ hf){
  __shared__ float xS[16*33];
  __shared__ __align__(16) ushort_t wS[NIN*HID];
  int t = threadIdx.x;
  int nb = blockIdx.x*16;
  {
    float2 v = *(const float2*)(x + (size_t)nb*NIN + t*2);
    int idx = t*2;
    int r = idx >> 5, k = idx & 31;
    xS[r*33 + k]     = v.x;
    xS[r*33 + k + 1] = v.y;
  }
  stage16((const char*)wemb2 + t*16,        (char*)wS + t*16);
  stage16((const char*)wemb2 + 4096 + t*16, (char*)wS + 4096 + t*16);
  __syncthreads();

  int r = t >> 4, c0 = (t & 15)*8;
  h2 a0, a1, a2, a3;
  a0 = a1 = a2 = a3 = u2h(0u);
  #pragma unroll
  for (int k = 0; k < NIN; ++k){
    float xk = xS[r*33 + k];
    h2 xp = __builtin_amdgcn_cvt_pkrtz(xk, xk);
    uint4 wv = *(const uint4*)&wS[k*HID + c0];
    a0 = __builtin_elementwise_fma(xp, u2h(wv.x), a0);
    a1 = __builtin_elementwise_fma(xp, u2h(wv.y), a1);
    a2 = __builtin_elementwise_fma(xp, u2h(wv.z), a2);
    a3 = __builtin_elementwise_fma(xp, u2h(wv.w), a3);
  }
  float4 bv0 = *(const float4*)&b[c0];
  float4 bv1 = *(const float4*)&b[c0 + 4];
  a0 = a0 + __builtin_amdgcn_cvt_pkrtz(bv0.x, bv0.y);
  a1 = a1 + __builtin_amdgcn_cvt_pkrtz(bv0.z, bv0.w);
  a2 = a2 + __builtin_amdgcn_cvt_pkrtz(bv1.x, bv1.y);
  a3 = a3 + __builtin_amdgcn_cvt_pkrtz(bv1.z, bv1.w);
  uint4 o;
  o.x = h2u(a0); o.y = h2u(a1); o.z = h2u(a2); o.w = h2u(a3);
  *(uint4*)&hf[(size_t)(nb + r)*HID + c0] = o;
}

// ======================= GINE aggregate v7: split dep-chains + exact wave balance =======================
// Writes the FULL MLP input A = (1+eps)*h + sum_e relu(h_src + ea@W + b), f16,
// PRE-SWIZZLED (halfword idx c ^ ((n&7)<<3)) so kMlp stages it via global_load_lds.
__global__ __launch_bounds__(256) void kAgg(
    const ushort_t* __restrict__ hf, const unsigned* __restrict__ eaPos,
    const int* __restrict__ srcPos, const int* __restrict__ offs,
    const float* __restrict__ Wl, const float* __restrict__ bl,
    const float* __restrict__ epsArr, int layer,
    ushort_t* __restrict__ ab, float* __restrict__ bnS, float* __restrict__ bnQ){
  __shared__ unsigned easu[4][16][8];   // [wave][edge][8 u32 = 16 f16 k-values]
  __shared__ int srcsS[4][16];
  int tid = threadIdx.x, lane = tid & 63, wv = tid >> 6;
  if (blockIdx.x == 0 && tid < 128){ bnS[tid] = 0.f; bnQ[tid] = 0.f; }
  int c0 = 2*lane;
  h2 wP[EIN];
  #pragma unroll
  for (int k = 0; k < EIN; ++k)
    wP[k] = __builtin_amdgcn_cvt_pkrtz(Wl[k*HID + c0], Wl[k*HID + c0 + 1]);
  h2 biasP = __builtin_amdgcn_cvt_pkrtz(bl[c0], bl[c0+1]);
  float one = 1.0f;
  float ep1 = 1.f + epsArr[layer];

  for (int n = blockIdx.x*4 + wv; n < NN; n += NB_AGG*4){
    int s0 = offs[n], s1 = offs[n+1];
    // split f32 accumulators (even/odd edge index) to break fma_mix chains
    float acc0a = 0.f, acc0b = 0.f, acc1a = 0.f, acc1b = 0.f;

    auto BODY = [&](int i, unsigned hs, float& a0, float& a1){
      const uint4* A = (const uint4*)&easu[wv][i][0];
      uint4 e0 = A[0], e1 = A[1];
      // split f16 edge-Lin into two independent chains of 8
      h2 aE = biasP;
      h2 aO; aO[0] = (__fp16)0.f; aO[1] = (__fp16)0.f;
      PKFMA_LO(aE, e0.x, wP[0]);  PKFMA_HI(aO, e0.x, wP[1]);
      PKFMA_LO(aE, e0.y, wP[2]);  PKFMA_HI(aO, e0.y, wP[3]);
      PKFMA_LO(aE, e0.z, wP[4]);  PKFMA_HI(aO, e0.z, wP[5]);
      PKFMA_LO(aE, e0.w, wP[6]);  PKFMA_HI(aO, e0.w, wP[7]);
      PKFMA_LO(aE, e1.x, wP[8]);  PKFMA_HI(aO, e1.x, wP[9]);
      PKFMA_LO(aE, e1.y, wP[10]); PKFMA_HI(aO, e1.y, wP[11]);
      PKFMA_LO(aE, e1.z, wP[12]); PKFMA_HI(aO, e1.z, wP[13]);
      PKFMA_LO(aE, e1.w, wP[14]); PKFMA_HI(aO, e1.w, wP[15]);
      h2 t = (aE + aO) + u2h(hs);
      h2 zz; zz[0] = (__fp16)0.f; zz[1] = (__fp16)0.f;
      t = __builtin_elementwise_max(t, zz);
      FMAMIX_LO(a0, t, one);
      FMAMIX_HI(a1, t, one);
    };

    for (int j = s0; j < s1; j += 16){
      int cnt = min(16, s1 - j);
      if (lane < cnt) srcsS[wv][lane] = srcPos[j + lane];
      if (lane < 4*cnt){
        int r = lane >> 2, part = lane & 3;
        *(uint2*)&easu[wv][r][part*2] = *(const uint2*)&eaPos[(size_t)(j + r)*8 + part*2];
      }
      asm volatile("s_waitcnt lgkmcnt(0)" ::: "memory");
      if (cnt == 16){
        unsigned hsv[16];
        #pragma unroll
        for (int i = 0; i < 16; ++i)
          hsv[i] = *(const unsigned*)&hf[(size_t)srcsS[wv][i]*HID + c0];
        #pragma unroll
        for (int i = 0; i < 16; ++i){
          if (i & 1) BODY(i, hsv[i], acc0b, acc1b);
          else       BODY(i, hsv[i], acc0a, acc1a);
        }
      } else {
        for (int i = 0; i < cnt; ++i){
          unsigned hs = *(const unsigned*)&hf[(size_t)srcsS[wv][i]*HID + c0];
          if (i & 1) BODY(i, hs, acc0b, acc1b);
          else       BODY(i, hs, acc0a, acc1a);
        }
      }
      asm volatile("s_waitcnt lgkmcnt(0)" ::: "memory");  // easu reads done before overwrite
    }
    unsigned hw = *(const unsigned*)&hf[(size_t)n*HID + c0];
    h2 hv = u2h(hw);
    float z0 = fmaf(ep1, (float)hv[0], acc0a + acc0b);
    float z1 = fmaf(ep1, (float)hv[1], acc1a + acc1b);
    *(unsigned*)&ab[(size_t)n*HID + (c0 ^ ((n & 7) << 3))] = pkf16(z0, z1);
  }
}

// ======================= fused MLP via MFMA (f16): z2 = relu(A@W1+b1)@W2+b2 =======================
// A staged directly via global_load_lds (kAgg pre-swizzled it). z2 out f16 + BN partial stats.
__global__ __launch_bounds__(256, 1) void kMlp(
    const ushort_t* __restrict__ ab, ushort_t* __restrict__ z2,
    const ushort_t* __restrict__ w1t, const float* __restrict__ b1,
    const ushort_t* __restrict__ w2t, const float* __restrict__ b2,
    float* __restrict__ bnS, float* __restrict__ bnQ){
  __shared__ __align__(16) ushort_t As[BM*128];
  __shared__ __align__(16) ushort_t Bs[128*128];
  __shared__ float red[256];
  int tid  = threadIdx.x;
  int lane = tid & 63;
  int w    = tid >> 6;
  int ln   = tid & 15;
  int q    = (tid >> 4) & 3;
  int rbase = blockIdx.x * BM;
  int m0 = (w >> 1) * 32;
  int wc = (w & 1) * 64;

  const char* gA = (const char*)(ab + (size_t)rbase * HID);
  #pragma unroll
  for (int it = 0; it < 4; ++it)
    stage16(gA + (w*4096 + it*1024 + lane*16), (char*)As + (w*4096 + it*1024));
  const char* gB1 = (const char*)w1t;
  #pragma unroll
  for (int it = 0; it < 8; ++it)
    stage16(gB1 + (w*8192 + it*1024 + lane*16), (char*)Bs + (w*8192 + it*1024));
  __syncthreads();

  f32x4 acc[2][4];
  #pragma unroll
  for (int i = 0; i < 2; ++i)
    #pragma unroll
    for (int j = 0; j < 4; ++j) acc[i][j] = (f32x4)0.f;

  #pragma unroll
  for (int kk = 0; kk < 4; ++kk){
    int kb = kk*32 + q*8;
    half8 af[2], bf[4];
    #pragma unroll
    for (int i = 0; i < 2; ++i){
      int m = m0 + 16*i + ln;
      af[i] = *(const half8*)&As[m*128 + (kb ^ ((m&7)<<3))];
    }
    #pragma unroll
    for (int j = 0; j < 4; ++j){
      int nn = wc + 16*j + ln;
      bf[j] = *(const half8*)&Bs[nn*128 + (kb ^ ((nn&7)<<3))];
    }
    #pragma unroll
    for (int i = 0; i < 2; ++i)
      #pragma unroll
      for (int j = 0; j < 4; ++j)
        acc[i][j] = __builtin_amdgcn_mfma_f32_16x16x32_f16(af[i], bf[j], acc[i][j], 0, 0, 0);
  }
  __syncthreads();

  const char* gB2 = (const char*)w2t;
  #pragma unroll
  for (int it = 0; it < 8; ++it)
    stage16(gB2 + (w*8192 + it*1024 + lane*16), (char*)Bs + (w*8192 + it*1024));
  {
    float b1v[4];
    #pragma unroll
    for (int j = 0; j < 4; ++j) b1v[j] = b1[wc + 16*j + ln];
    #pragma unroll
    for (int i = 0; i < 2; ++i){
      #pragma unroll
      for (int j = 0; j < 4; ++j){
        int kc = wc + 16*j + ln;
        #pragma unroll
        for (int r = 0; r < 4; ++r){
          int m = m0 + 16*i + 4*q + r;
          As[m*128 + (kc ^ ((m&7)<<3))] = f2h(fmaxf(acc[i][j][r] + b1v[j], 0.f));
        }
      }
    }
  }
  #pragma unroll
  for (int i = 0; i < 2; ++i)
    #pragma unroll
    for (int j = 0; j < 4; ++j) acc[i][j] = (f32x4)0.f;
  __syncthreads();

  #pragma unroll
  for (int kk = 0; kk < 4; ++kk){
    int kb = kk*32 + q*8;
    half8 af[2], bf[4];
    #pragma unroll
    for (int i = 0; i < 2; ++i){
      int m = m0 + 16*i + ln;
      af[i] = *(const half8*)&As[m*128 + (kb ^ ((m&7)<<3))];
    }
    #pragma unroll
    for (int j = 0; j < 4; ++j){
      int nn = wc + 16*j + ln;
      bf[j] = *(const half8*)&Bs[nn*128 + (kb ^ ((nn&7)<<3))];
    }
    #pragma unroll
    for (int i = 0; i < 2; ++i)
      #pragma unroll
      for (int j = 0; j < 4; ++j)
        acc[i][j] = __builtin_amdgcn_mfma_f32_16x16x32_f16(af[i], bf[j], acc[i][j], 0, 0, 0);
  }

  float b2v[4];
  #pragma unroll
  for (int j = 0; j < 4; ++j) b2v[j] = b2[wc + 16*j + ln];
  float ps[4], pq[4];
  #pragma unroll
  for (int j = 0; j < 4; ++j){ ps[j] = 0.f; pq[j] = 0.f; }
  #pragma unroll
  for (int i = 0; i < 2; ++i){
    #pragma unroll
    for (int r = 0; r < 4; ++r){
      int rg = rbase + m0 + 16*i + 4*q + r;
      if (rg < NN){
        #pragma unroll
        for (int j = 0; j < 4; ++j){
          float v = acc[i][j][r] + b2v[j];
          z2[(size_t)rg*HID + wc + 16*j + ln] = f2h(v);
          ps[j] += v; pq[j] += v*v;
        }
      }
    }
  }
  red[tid] = 0.f;
  if (tid < 128) red[128 + tid] = 0.f;
  __syncthreads();
  #pragma unroll
  for (int j = 0; j < 4; ++j){
    int c = wc + 16*j + ln;
    atomicAdd(&red[c], ps[j]);
    atomicAdd(&red[128 + c], pq[j]);
  }
  __syncthreads();
  if (tid < 128){
    atomicAdd(&bnS[tid], red[tid]);
    atomicAdd(&bnQ[tid], red[128 + tid]);
  }
}

// ======================= BN apply + ReLU -> hf (f16, reads f16 z2) =======================
__global__ void kBn(const ushort_t* __restrict__ z2, const float* __restrict__ bnS,
                    const float* __restrict__ bnQ, const float* __restrict__ gamma,
                    const float* __restrict__ beta, ushort_t* __restrict__ hf){
  int gid = blockIdx.x*256 + threadIdx.x;   // NN*64
  if (gid >= NN*64) return;
  int r = gid >> 6, c = (gid & 63)*2;
  unsigned zu = *(const unsigned*)&z2[(size_t)r*HID + c];
  float z0 = h2f((ushort_t)(zu & 0xffffu)), z1 = h2f((ushort_t)(zu >> 16));
  float2 sS = *(const float2*)&bnS[c];
  float2 sQ = *(const float2*)&bnQ[c];
  float2 gm = *(const float2*)&gamma[c];
  float2 bt = *(const float2*)&beta[c];
  float m0 = sS.x*(1.f/NN), m1 = sS.y*(1.f/NN);
  float v0 = sQ.x*(1.f/NN) - m0*m0, v1 = sQ.y*(1.f/NN) - m1*m1;
  float o0 = fmaxf((z0 - m0)*rsqrtf(v0 + 1e-5f)*gm.x + bt.x, 0.f);
  float o1 = fmaxf((z1 - m1)*rsqrtf(v1 + 1e-5f)*gm.y + bt.y, 0.f);
  *(unsigned*)&hf[(size_t)r*HID + c] = pkf16(o0, o1);
}

// ======================= fused pool + head =======================
__global__ __launch_bounds__(192) void kPoolHead(const ushort_t* __restrict__ hf,
    const int* __restrict__ bid, const int* __restrict__ tidx,
    const float* __restrict__ temb,
    const float* __restrict__ w1, const float* __restrict__ b1,
    const float* __restrict__ w2, const float* __restrict__ b2,
    const float* __restrict__ w3, const float* __restrict__ b3,
    float* __restrict__ out){
  __shared__ float gv[192];
  __shared__ float t1[128];
  __shared__ float t2[64];
  int b = blockIdx.x, t = threadIdx.x;
  int lo = 0, hi = NN;
  while (lo < hi){ int m = (lo + hi) >> 1; if (bid[m] < b) lo = m + 1; else hi = m; }
  int s = lo;
  lo = 0; hi = NN;
  while (lo < hi){ int m = (lo + hi) >> 1; if (bid[m] < b + 1) lo = m + 1; else hi = m; }
  int e = lo;
  if (t < HID){
    float acc = 0.f;
    for (int n = s; n < e; ++n) acc += h2f(hf[(size_t)n*HID + t]);
    gv[t] = acc;
  } else {
    gv[t] = temb[tidx[b]*TE + (t - HID)];
  }
  __syncthreads();
  float acc = b1[t & 127];
  if (t < HID){
    for (int k = 0; k < 192; ++k) acc = fmaf(gv[k], w1[k*HID + t], acc);
    t1[t] = fmaxf(acc, 0.f);
  }
  __syncthreads();
  if (t < 64){
    float a2 = b2[t];
    for (int k = 0; k < 128; ++k) a2 = fmaf(t1[k], w2[k*64 + t], a2);
    t2[t] = fmaxf(a2, 0.f);
  }
  __syncthreads();
  if (t == 0){
    float sv = b3[0];
    for (int k = 0; k < 64; ++k) sv = fmaf(t2[k], w3[k], sv);
    out[b] = sv;
  }
}

// ======================= launch =======================
extern "C" void kernel_launch(void* const* d_in, const int* in_sizes, int n_in,
                              void* d_out, int out_size, void* d_ws, size_t ws_size,
                              hipStream_t stream){
  const float* x     = (const float*)d_in[0];
  const int*   ei    = (const int*)  d_in[1];
  const float* eattr = (const float*)d_in[2];
  const int*   bids  = (const int*)  d_in[3];
  const int*   tgt   = (const int*)  d_in[4];
  const float* nw    = (const float*)d_in[5];
  const float* nb    = (const float*)d_in[6];
  const float* eps   = (const float*)d_in[7];
  const float* ew    = (const float*)d_in[8];
  const float* eb    = (const float*)d_in[9];
  const float* w1    = (const float*)d_in[10];
  const float* bb1   = (const float*)d_in[11];
  const float* w2    = (const float*)d_in[12];
  const float* bb2   = (const float*)d_in[13];
  const float* gam   = (const float*)d_in[14];
  const float* bet   = (const float*)d_in[15];
  const float* temb  = (const float*)d_in[16];
  const float* h1w   = (const float*)d_in[17];
  const float* h1b   = (const float*)d_in[18];
  const float* h2w   = (const float*)d_in[19];
  const float* h2b   = (const float*)d_in[20];
  const float* h3w   = (const float*)d_in[21];
  const float* h3b   = (const float*)d_in[22];
  float* out = (float*)d_out;

  ushort_t* ab   = (ushort_t*)d_ws;                     // (NN+64)*128
  ushort_t* wtb  = ab + (size_t)(NN + 64)*HID;          // 6*16384
  ushort_t* wemb2= wtb + (size_t)6*16384;               // NIN*HID
  ushort_t* hf   = wemb2 + (size_t)NIN*HID;             // (NN+64)*128
  ushort_t* z2   = hf + (size_t)(NN + 64)*HID;          // NN*128 (f16)
  unsigned* eaPos = (unsigned*)(z2 + (size_t)NN*HID);   // NE*8
  float* bnS = (float*)(eaPos + (size_t)NE*8);          // 128
  float* bnQ = bnS + HID;                               // 128
  int* offs  = (int*)(bnQ + HID);                       // NN+1
  int* cnt   = offs + NN + 1;                           // NN
  int* curs  = cnt + NN;                                // NN
  int* perm  = curs + NN;                               // NE
  int* srcPos= perm + NE;                               // NE
  int* psum  = srcPos + NE;                             // 256
  int* pofs  = psum + 256;                              // 256

  const int* esrc = ei;
  const int* edst = ei + NE;

  kConvW      <<<(6*16384 + NIN*HID + NN + 255)/256, 256, 0, stream>>>(w1, w2, nw, wtb, wemb2, cnt);
  kHist       <<<(NE + 255)/256, 256, 0, stream>>>(edst, cnt);
  kPartSum    <<<SCAN_B, 256, 0, stream>>>(cnt, psum);
  kScanPart   <<<1, 256, 0, stream>>>(psum, pofs, offs);
  kScanApply  <<<SCAN_B, 256, 0, stream>>>(cnt, pofs, offs, curs);
  kScatterPerm<<<(NE + 255)/256, 256, 0, stream>>>(edst, curs, perm);
  kGatherEA   <<<(NE + 255)/256, 256, 0, stream>>>(perm, esrc, eattr, srcPos, eaPos);
  kNodeInit2  <<<NN/16, 256, 0, stream>>>(x, wemb2, nb, hf);

  for (int l = 0; l < NL; ++l){
    kAgg<<<NB_AGG, 256, 0, stream>>>(hf, eaPos, srcPos, offs,
                                 ew + (size_t)l*EIN*HID, eb + (size_t)l*HID, eps, l,
                                 ab, bnS, bnQ);
    kMlp<<<(NN + BM - 1)/BM, 256, 0, stream>>>(ab, z2,
                                 wtb + (size_t)l*16384, bb1 + (size_t)l*HID,
                                 wtb + (size_t)(3+l)*16384, bb2 + (size_t)l*HID,
                                 bnS, bnQ);
    kBn<<<(NN*64 + 255)/256, 256, 0, stream>>>(z2, bnS, bnQ,
                                 gam + (size_t)l*HID, bet + (size_t)l*HID, hf);
  }

  kPoolHead<<<NG, 192, 0, stream>>>(hf, bids, tgt, temb,
                                    h1w, h1b, h2w, h2b, h3w, h3b, out);
}

// Round 17
// 521.172 us; speedup vs baseline: 1.0806x; 1.0806x over previous
//
#include <hip/hip_runtime.h>

#define NN 50000
#define NE 800000
#define NIN 32
#define EIN 16
#define HID 128
#define NL 3
#define NG 256
#define TE 64
#define BM 64        // kMlp row tile
#define SCAN_B 196   // ceil(NN/256)
#define NB_AGG 4096  // kAgg blocks (x4 waves)

typedef unsigned short ushort_t;
typedef __attribute__((ext_vector_type(8))) _Float16 half8;
typedef __attribute__((ext_vector_type(4))) float f32x4;
typedef __attribute__((ext_vector_type(2))) __fp16 h2;

__device__ __forceinline__ unsigned pkf16(float a, float b){
  h2 h = __builtin_amdgcn_cvt_pkrtz(a, b);
  union{ h2 h; unsigned u; } c; c.h = h; return c.u;
}
__device__ __forceinline__ h2 u2h(unsigned u){
  union{ unsigned u; h2 h; } c; c.u = u; return c.h;
}
__device__ __forceinline__ unsigned h2u(h2 h){
  union{ h2 h; unsigned u; } c; c.h = h; return c.u;
}
__device__ __forceinline__ ushort_t f2h(float x){
  union{ __fp16 h; ushort_t u; } c; c.h = (__fp16)x; return c.u;
}
__device__ __forceinline__ float h2f(ushort_t v){
  union{ ushort_t u; __fp16 h; } c; c.u = v; return (float)c.h;
}

// v_pk_fma_f16 with op_sel broadcast of src0 half (zero-cost scalar splat)
#define PKFMA_LO(a, e, w) asm("v_pk_fma_f16 %0, %1, %2, %0 op_sel:[0,0,0] op_sel_hi:[0,1,1]" : "+v"(a) : "v"(e), "v"(w))
#define PKFMA_HI(a, e, w) asm("v_pk_fma_f16 %0, %1, %2, %0 op_sel:[1,0,0] op_sel_hi:[1,1,1]" : "+v"(a) : "v"(e), "v"(w))
// acc(f32) += f16 half of t (single instruction f16->f32 accumulate)
#define FMAMIX_LO(acc, t, one) asm("v_fma_mix_f32 %0, %1, %2, %0 op_sel:[0,0,0] op_sel_hi:[1,0,0]" : "+v"(acc) : "v"(t), "v"(one))
#define FMAMIX_HI(acc, t, one) asm("v_fma_mix_f32 %0, %1, %2, %0 op_sel:[1,0,0] op_sel_hi:[1,0,0]" : "+v"(acc) : "v"(t), "v"(one))

typedef const __attribute__((address_space(1))) unsigned gas_t;
typedef __attribute__((address_space(3))) unsigned las_t;
__device__ __forceinline__ void stage16(const void* g, void* l){
  __builtin_amdgcn_global_load_lds((gas_t*)g, (las_t*)l, 16, 0, 0);
}

// ======================= CSR build (dst-sorted) =======================
__global__ void kHist(const int* __restrict__ dst, int* __restrict__ cnt){
  int e = blockIdx.x*256 + threadIdx.x;
  if (e < NE) atomicAdd(&cnt[dst[e]], 1);
}

__global__ void kPartSum(const int* __restrict__ cnt, int* __restrict__ psum){
  __shared__ int sm[256];
  int b = blockIdx.x, t = threadIdx.x, i = b*256 + t;
  sm[t] = (i < NN) ? cnt[i] : 0;
  __syncthreads();
  for (int o = 128; o > 0; o >>= 1){
    if (t < o) sm[t] += sm[t + o];
    __syncthreads();
  }
  if (t == 0) psum[b] = sm[0];
}

__global__ __launch_bounds__(256) void kScanPart(const int* __restrict__ psum,
                                                 int* __restrict__ pofs, int* __restrict__ offs){
  __shared__ int sm[256];
  int t = threadIdx.x;
  int v = (t < SCAN_B) ? psum[t] : 0;
  sm[t] = v;
  __syncthreads();
  for (int o = 1; o < 256; o <<= 1){
    int x = (t >= o) ? sm[t - o] : 0;
    __syncthreads();
    sm[t] += x;
    __syncthreads();
  }
  if (t < SCAN_B) pofs[t] = sm[t] - v;
  if (t == 255) offs[NN] = sm[255];
}

__global__ void kScanApply(const int* __restrict__ cnt, const int* __restrict__ pofs,
                           int* __restrict__ offs, int* __restrict__ curs){
  __shared__ int sm[256];
  int b = blockIdx.x, t = threadIdx.x, i = b*256 + t;
  int v = (i < NN) ? cnt[i] : 0;
  sm[t] = v;
  __syncthreads();
  for (int o = 1; o < 256; o <<= 1){
    int x = (t >= o) ? sm[t - o] : 0;
    __syncthreads();
    sm[t] += x;
    __syncthreads();
  }
  int ex = sm[t] - v + pofs[b];
  if (i < NN){ offs[i] = ex; curs[i] = ex; }
}

// scatter only the permutation (4B) — minimal scattered-write footprint
__global__ void kScatterPerm(const int* __restrict__ dst, int* __restrict__ curs,
                             int* __restrict__ perm){
  int e = blockIdx.x*256 + threadIdx.x;
  if (e < NE){
    int p = atomicAdd(&curs[dst[e]], 1);
    perm[p] = e;
  }
}

// gather side: coalesced over CSR positions; eattr rows are 64B-aligned full sectors
__global__ void kGatherEA(const int* __restrict__ perm, const int* __restrict__ src,
                          const float* __restrict__ eattr,
                          int* __restrict__ srcPos, unsigned* __restrict__ eaPos){
  int p = blockIdx.x*256 + threadIdx.x;
  if (p >= NE) return;
  int e = perm[p];
  srcPos[p] = src[e];
  const float4* row = (const float4*)(eattr + (size_t)e*EIN);
  float4 v0 = row[0], v1 = row[1], v2 = row[2], v3 = row[3];
  uint4 d0, d1;
  d0.x = pkf16(v0.x, v0.y); d0.y = pkf16(v0.z, v0.w);
  d0.z = pkf16(v1.x, v1.y); d0.w = pkf16(v1.z, v1.w);
  d1.x = pkf16(v2.x, v2.y); d1.y = pkf16(v2.z, v2.w);
  d1.z = pkf16(v3.x, v3.y); d1.w = pkf16(v3.z, v3.w);
  *(uint4*)&eaPos[(size_t)p*8]     = d0;
  *(uint4*)&eaPos[(size_t)p*8 + 4] = d1;
}

// ======================= W -> f16 conversions + cnt zeroing (fused) =======================
__global__ void kConvW(const float* __restrict__ w1, const float* __restrict__ w2,
                       const float* __restrict__ nw,
                       ushort_t* __restrict__ wtb, ushort_t* __restrict__ wemb2,
                       int* __restrict__ cnt){
  int gid = blockIdx.x*256 + threadIdx.x;
  if (gid < 6*16384){
    int mat = gid >> 14, idx = gid & 16383;
    int k = idx >> 7, n = idx & 127;
    const float* src = (mat < 3) ? (w1 + (size_t)mat*16384) : (w2 + (size_t)(mat-3)*16384);
    wtb[(size_t)mat*16384 + n*128 + (k ^ ((n&7)<<3))] = f2h(src[idx]);
  } else if (gid < 6*16384 + NIN*HID){
    int i = gid - 6*16384;
    wemb2[i] = f2h(nw[i]);
  } else {
    int i = gid - (6*16384 + NIN*HID);
    if (i < NN) cnt[i] = 0;
  }
}

// ======================= node embed -> hf (f16), LDS-staged =======================
__global__ __launch_bounds__(256) void kNodeInit2(const float* __restrict__ x,
    const ushort_t* __restrict__ wemb2, const float* __restrict__ b,
    ushort_t* __restrict__ hf){
  __shared__ float xS[16*33];
  __shared__ __align__(16) ushort_t wS[NIN*HID];
  int t = threadIdx.x;
  int nb = blockIdx.x*16;
  {
    float2 v = *(const float2*)(x + (size_t)nb*NIN + t*2);
    int idx = t*2;
    int r = idx >> 5, k = idx & 31;
    xS[r*33 + k]     = v.x;
    xS[r*33 + k + 1] = v.y;
  }
  stage16((const char*)wemb2 + t*16,        (char*)wS + t*16);
  stage16((const char*)wemb2 + 4096 + t*16, (char*)wS + 4096 + t*16);
  __syncthreads();

  int r = t >> 4, c0 = (t & 15)*8;
  h2 a0, a1, a2, a3;
  a0 = a1 = a2 = a3 = u2h(0u);
  #pragma unroll
  for (int k = 0; k < NIN; ++k){
    float xk = xS[r*33 + k];
    h2 xp = __builtin_amdgcn_cvt_pkrtz(xk, xk);
    uint4 wv = *(const uint4*)&wS[k*HID + c0];
    a0 = __builtin_elementwise_fma(xp, u2h(wv.x), a0);
    a1 = __builtin_elementwise_fma(xp, u2h(wv.y), a1);
    a2 = __builtin_elementwise_fma(xp, u2h(wv.z), a2);
    a3 = __builtin_elementwise_fma(xp, u2h(wv.w), a3);
  }
  float4 bv0 = *(const float4*)&b[c0];
  float4 bv1 = *(const float4*)&b[c0 + 4];
  a0 = a0 + __builtin_amdgcn_cvt_pkrtz(bv0.x, bv0.y);
  a1 = a1 + __builtin_amdgcn_cvt_pkrtz(bv0.z, bv0.w);
  a2 = a2 + __builtin_amdgcn_cvt_pkrtz(bv1.x, bv1.y);
  a3 = a3 + __builtin_amdgcn_cvt_pkrtz(bv1.z, bv1.w);
  uint4 o;
  o.x = h2u(a0); o.y = h2u(a1); o.z = h2u(a2); o.w = h2u(a3);
  *(uint4*)&hf[(size_t)(nb + r)*HID + c0] = o;
}

// ======================= GINE aggregate (R15-proven): LDS-staged batches + op_sel pk_fma =======================
// Writes the FULL MLP input A = (1+eps)*h + sum_e relu(h_src + ea@W + b), f16,
// PRE-SWIZZLED (halfword idx c ^ ((n&7)<<3)) so kMlp stages it via global_load_lds.
__global__ __launch_bounds__(256) void kAgg(
    const ushort_t* __restrict__ hf, const unsigned* __restrict__ eaPos,
    const int* __restrict__ srcPos, const int* __restrict__ offs,
    const float* __restrict__ Wl, const float* __restrict__ bl,
    const float* __restrict__ epsArr, int layer,
    ushort_t* __restrict__ ab, float* __restrict__ bnS, float* __restrict__ bnQ){
  __shared__ unsigned easu[4][16][8];   // [wave][edge][8 u32 = 16 f16 k-values]
  __shared__ int srcsS[4][16];
  int tid = threadIdx.x, lane = tid & 63, wv = tid >> 6;
  if (blockIdx.x == 0 && tid < 128){ bnS[tid] = 0.f; bnQ[tid] = 0.f; }
  int c0 = 2*lane;
  h2 wP[EIN];
  #pragma unroll
  for (int k = 0; k < EIN; ++k)
    wP[k] = __builtin_amdgcn_cvt_pkrtz(Wl[k*HID + c0], Wl[k*HID + c0 + 1]);
  h2 biasP = __builtin_amdgcn_cvt_pkrtz(bl[c0], bl[c0+1]);
  float one = 1.0f;
  float ep1 = 1.f + epsArr[layer];

  for (int n = blockIdx.x*4 + wv; n < NN; n += NB_AGG*4){
    int s0 = offs[n], s1 = offs[n+1];
    float acc0 = 0.f, acc1 = 0.f;

    auto BODY = [&](int i, unsigned hs){
      const uint4* A = (const uint4*)&easu[wv][i][0];
      uint4 e0 = A[0], e1 = A[1];
      h2 a = biasP;
      PKFMA_LO(a, e0.x, wP[0]);  PKFMA_HI(a, e0.x, wP[1]);
      PKFMA_LO(a, e0.y, wP[2]);  PKFMA_HI(a, e0.y, wP[3]);
      PKFMA_LO(a, e0.z, wP[4]);  PKFMA_HI(a, e0.z, wP[5]);
      PKFMA_LO(a, e0.w, wP[6]);  PKFMA_HI(a, e0.w, wP[7]);
      PKFMA_LO(a, e1.x, wP[8]);  PKFMA_HI(a, e1.x, wP[9]);
      PKFMA_LO(a, e1.y, wP[10]); PKFMA_HI(a, e1.y, wP[11]);
      PKFMA_LO(a, e1.z, wP[12]); PKFMA_HI(a, e1.z, wP[13]);
      PKFMA_LO(a, e1.w, wP[14]); PKFMA_HI(a, e1.w, wP[15]);
      h2 t = a + u2h(hs);
      h2 zz; zz[0] = (__fp16)0.f; zz[1] = (__fp16)0.f;
      t = __builtin_elementwise_max(t, zz);
      FMAMIX_LO(acc0, t, one);
      FMAMIX_HI(acc1, t, one);
    };

    for (int j = s0; j < s1; j += 16){
      int cnt = min(16, s1 - j);
      if (lane < cnt) srcsS[wv][lane] = srcPos[j + lane];
      if (lane < 4*cnt){
        int r = lane >> 2, part = lane & 3;
        *(uint2*)&easu[wv][r][part*2] = *(const uint2*)&eaPos[(size_t)(j + r)*8 + part*2];
      }
      asm volatile("s_waitcnt lgkmcnt(0)" ::: "memory");
      if (cnt == 16){
        unsigned hsv[16];
        #pragma unroll
        for (int i = 0; i < 16; ++i)
          hsv[i] = *(const unsigned*)&hf[(size_t)srcsS[wv][i]*HID + c0];
        #pragma unroll
        for (int i = 0; i < 16; ++i) BODY(i, hsv[i]);
      } else {
        for (int i = 0; i < cnt; ++i){
          unsigned hs = *(const unsigned*)&hf[(size_t)srcsS[wv][i]*HID + c0];
          BODY(i, hs);
        }
      }
      asm volatile("s_waitcnt lgkmcnt(0)" ::: "memory");  // easu reads done before overwrite
    }
    unsigned hw = *(const unsigned*)&hf[(size_t)n*HID + c0];
    h2 hv = u2h(hw);
    float z0 = fmaf(ep1, (float)hv[0], acc0);
    float z1 = fmaf(ep1, (float)hv[1], acc1);
    *(unsigned*)&ab[(size_t)n*HID + (c0 ^ ((n & 7) << 3))] = pkf16(z0, z1);
  }
}

// ======================= fused MLP via MFMA (f16): z2 = relu(A@W1+b1)@W2+b2 =======================
// A staged directly via global_load_lds (kAgg pre-swizzled it). z2 out f16 + BN partial stats.
__global__ __launch_bounds__(256, 1) void kMlp(
    const ushort_t* __restrict__ ab, ushort_t* __restrict__ z2,
    const ushort_t* __restrict__ w1t, const float* __restrict__ b1,
    const ushort_t* __restrict__ w2t, const float* __restrict__ b2,
    float* __restrict__ bnS, float* __restrict__ bnQ){
  __shared__ __align__(16) ushort_t As[BM*128];
  __shared__ __align__(16) ushort_t Bs[128*128];
  __shared__ float red[256];
  int tid  = threadIdx.x;
  int lane = tid & 63;
  int w    = tid >> 6;
  int ln   = tid & 15;
  int q    = (tid >> 4) & 3;
  int rbase = blockIdx.x * BM;
  int m0 = (w >> 1) * 32;
  int wc = (w & 1) * 64;

  const char* gA = (const char*)(ab + (size_t)rbase * HID);
  #pragma unroll
  for (int it = 0; it < 4; ++it)
    stage16(gA + (w*4096 + it*1024 + lane*16), (char*)As + (w*4096 + it*1024));
  const char* gB1 = (const char*)w1t;
  #pragma unroll
  for (int it = 0; it < 8; ++it)
    stage16(gB1 + (w*8192 + it*1024 + lane*16), (char*)Bs + (w*8192 + it*1024));
  __syncthreads();

  f32x4 acc[2][4];
  #pragma unroll
  for (int i = 0; i < 2; ++i)
    #pragma unroll
    for (int j = 0; j < 4; ++j) acc[i][j] = (f32x4)0.f;

  #pragma unroll
  for (int kk = 0; kk < 4; ++kk){
    int kb = kk*32 + q*8;
    half8 af[2], bf[4];
    #pragma unroll
    for (int i = 0; i < 2; ++i){
      int m = m0 + 16*i + ln;
      af[i] = *(const half8*)&As[m*128 + (kb ^ ((m&7)<<3))];
    }
    #pragma unroll
    for (int j = 0; j < 4; ++j){
      int nn = wc + 16*j + ln;
      bf[j] = *(const half8*)&Bs[nn*128 + (kb ^ ((nn&7)<<3))];
    }
    #pragma unroll
    for (int i = 0; i < 2; ++i)
      #pragma unroll
      for (int j = 0; j < 4; ++j)
        acc[i][j] = __builtin_amdgcn_mfma_f32_16x16x32_f16(af[i], bf[j], acc[i][j], 0, 0, 0);
  }
  __syncthreads();

  const char* gB2 = (const char*)w2t;
  #pragma unroll
  for (int it = 0; it < 8; ++it)
    stage16(gB2 + (w*8192 + it*1024 + lane*16), (char*)Bs + (w*8192 + it*1024));
  {
    float b1v[4];
    #pragma unroll
    for (int j = 0; j < 4; ++j) b1v[j] = b1[wc + 16*j + ln];
    #pragma unroll
    for (int i = 0; i < 2; ++i){
      #pragma unroll
      for (int j = 0; j < 4; ++j){
        int kc = wc + 16*j + ln;
        #pragma unroll
        for (int r = 0; r < 4; ++r){
          int m = m0 + 16*i + 4*q + r;
          As[m*128 + (kc ^ ((m&7)<<3))] = f2h(fmaxf(acc[i][j][r] + b1v[j], 0.f));
        }
      }
    }
  }
  #pragma unroll
  for (int i = 0; i < 2; ++i)
    #pragma unroll
    for (int j = 0; j < 4; ++j) acc[i][j] = (f32x4)0.f;
  __syncthreads();

  #pragma unroll
  for (int kk = 0; kk < 4; ++kk){
    int kb = kk*32 + q*8;
    half8 af[2], bf[4];
    #pragma unroll
    for (int i = 0; i < 2; ++i){
      int m = m0 + 16*i + ln;
      af[i] = *(const half8*)&As[m*128 + (kb ^ ((m&7)<<3))];
    }
    #pragma unroll
    for (int j = 0; j < 4; ++j){
      int nn = wc + 16*j + ln;
      bf[j] = *(const half8*)&Bs[nn*128 + (kb ^ ((nn&7)<<3))];
    }
    #pragma unroll
    for (int i = 0; i < 2; ++i)
      #pragma unroll
      for (int j = 0; j < 4; ++j)
        acc[i][j] = __builtin_amdgcn_mfma_f32_16x16x32_f16(af[i], bf[j], acc[i][j], 0, 0, 0);
  }

  float b2v[4];
  #pragma unroll
  for (int j = 0; j < 4; ++j) b2v[j] = b2[wc + 16*j + ln];
  float ps[4], pq[4];
  #pragma unroll
  for (int j = 0; j < 4; ++j){ ps[j] = 0.f; pq[j] = 0.f; }
  #pragma unroll
  for (int i = 0; i < 2; ++i){
    #pragma unroll
    for (int r = 0; r < 4; ++r){
      int rg = rbase + m0 + 16*i + 4*q + r;
      if (rg < NN){
        #pragma unroll
        for (int j = 0; j < 4; ++j){
          float v = acc[i][j][r] + b2v[j];
          z2[(size_t)rg*HID + wc + 16*j + ln] = f2h(v);
          ps[j] += v; pq[j] += v*v;
        }
      }
    }
  }
  red[tid] = 0.f;
  if (tid < 128) red[128 + tid] = 0.f;
  __syncthreads();
  #pragma unroll
  for (int j = 0; j < 4; ++j){
    int c = wc + 16*j + ln;
    atomicAdd(&red[c], ps[j]);
    atomicAdd(&red[128 + c], pq[j]);
  }
  __syncthreads();
  if (tid < 128){
    atomicAdd(&bnS[tid], red[tid]);
    atomicAdd(&bnQ[tid], red[128 + tid]);
  }
}

// ======================= BN apply + ReLU -> hf (f16, reads f16 z2) =======================
__global__ void kBn(const ushort_t* __restrict__ z2, const float* __restrict__ bnS,
                    const float* __restrict__ bnQ, const float* __restrict__ gamma,
                    const float* __restrict__ beta, ushort_t* __restrict__ hf){
  int gid = blockIdx.x*256 + threadIdx.x;   // NN*64
  if (gid >= NN*64) return;
  int r = gid >> 6, c = (gid & 63)*2;
  unsigned zu = *(const unsigned*)&z2[(size_t)r*HID + c];
  float z0 = h2f((ushort_t)(zu & 0xffffu)), z1 = h2f((ushort_t)(zu >> 16));
  float2 sS = *(const float2*)&bnS[c];
  float2 sQ = *(const float2*)&bnQ[c];
  float2 gm = *(const float2*)&gamma[c];
  float2 bt = *(const float2*)&beta[c];
  float m0 = sS.x*(1.f/NN), m1 = sS.y*(1.f/NN);
  float v0 = sQ.x*(1.f/NN) - m0*m0, v1 = sQ.y*(1.f/NN) - m1*m1;
  float o0 = fmaxf((z0 - m0)*rsqrtf(v0 + 1e-5f)*gm.x + bt.x, 0.f);
  float o1 = fmaxf((z1 - m1)*rsqrtf(v1 + 1e-5f)*gm.y + bt.y, 0.f);
  *(unsigned*)&hf[(size_t)r*HID + c] = pkf16(o0, o1);
}

// ======================= fused pool + head (last-layer BN applied inline from z2) =======================
__global__ __launch_bounds__(192) void kPoolHead(const ushort_t* __restrict__ z2,
    const float* __restrict__ bnS, const float* __restrict__ bnQ,
    const float* __restrict__ gamma, const float* __restrict__ beta,
    const int* __restrict__ bid, const int* __restrict__ tidx,
    const float* __restrict__ temb,
    const float* __restrict__ w1, const float* __restrict__ b1,
    const float* __restrict__ w2, const float* __restrict__ b2,
    const float* __restrict__ w3, const float* __restrict__ b3,
    float* __restrict__ out){
  __shared__ float gv[192];
  __shared__ float t1[128];
  __shared__ float t2[64];
  int b = blockIdx.x, t = threadIdx.x;
  int lo = 0, hi = NN;
  while (lo < hi){ int m = (lo + hi) >> 1; if (bid[m] < b) lo = m + 1; else hi = m; }
  int s = lo;
  lo = 0; hi = NN;
  while (lo < hi){ int m = (lo + hi) >> 1; if (bid[m] < b + 1) lo = m + 1; else hi = m; }
  int e = lo;
  if (t < HID){
    float mean = bnS[t] * (1.f/NN);
    float var  = bnQ[t] * (1.f/NN) - mean*mean;
    float scl  = rsqrtf(var + 1e-5f) * gamma[t];
    float sft  = beta[t] - mean*scl;
    float acc = 0.f;
    for (int n = s; n < e; ++n)
      acc += fmaxf(fmaf(h2f(z2[(size_t)n*HID + t]), scl, sft), 0.f);
    gv[t] = acc;
  } else {
    gv[t] = temb[tidx[b]*TE + (t - HID)];
  }
  __syncthreads();
  float acc = b1[t & 127];
  if (t < HID){
    for (int k = 0; k < 192; ++k) acc = fmaf(gv[k], w1[k*HID + t], acc);
    t1[t] = fmaxf(acc, 0.f);
  }
  __syncthreads();
  if (t < 64){
    float a2 = b2[t];
    for (int k = 0; k < 128; ++k) a2 = fmaf(t1[k], w2[k*64 + t], a2);
    t2[t] = fmaxf(a2, 0.f);
  }
  __syncthreads();
  if (t == 0){
    float sv = b3[0];
    for (int k = 0; k < 64; ++k) sv = fmaf(t2[k], w3[k], sv);
    out[b] = sv;
  }
}

// ======================= launch =======================
extern "C" void kernel_launch(void* const* d_in, const int* in_sizes, int n_in,
                              void* d_out, int out_size, void* d_ws, size_t ws_size,
                              hipStream_t stream){
  const float* x     = (const float*)d_in[0];
  const int*   ei    = (const int*)  d_in[1];
  const float* eattr = (const float*)d_in[2];
  const int*   bids  = (const int*)  d_in[3];
  const int*   tgt   = (const int*)  d_in[4];
  const float* nw    = (const float*)d_in[5];
  const float* nb    = (const float*)d_in[6];
  const float* eps   = (const float*)d_in[7];
  const float* ew    = (const float*)d_in[8];
  const float* eb    = (const float*)d_in[9];
  const float* w1    = (const float*)d_in[10];
  const float* bb1   = (const float*)d_in[11];
  const float* w2    = (const float*)d_in[12];
  const float* bb2   = (const float*)d_in[13];
  const float* gam   = (const float*)d_in[14];
  const float* bet   = (const float*)d_in[15];
  const float* temb  = (const float*)d_in[16];
  const float* h1w   = (const float*)d_in[17];
  const float* h1b   = (const float*)d_in[18];
  const float* h2w   = (const float*)d_in[19];
  const float* h2b   = (const float*)d_in[20];
  const float* h3w   = (const float*)d_in[21];
  const float* h3b   = (const float*)d_in[22];
  float* out = (float*)d_out;

  ushort_t* ab   = (ushort_t*)d_ws;                     // (NN+64)*128
  ushort_t* wtb  = ab + (size_t)(NN + 64)*HID;          // 6*16384
  ushort_t* wemb2= wtb + (size_t)6*16384;               // NIN*HID
  ushort_t* hf   = wemb2 + (size_t)NIN*HID;             // (NN+64)*128
  ushort_t* z2   = hf + (size_t)(NN + 64)*HID;          // NN*128 (f16)
  unsigned* eaPos = (unsigned*)(z2 + (size_t)NN*HID);   // NE*8
  float* bnS = (float*)(eaPos + (size_t)NE*8);          // 128
  float* bnQ = bnS + HID;                               // 128
  int* offs  = (int*)(bnQ + HID);                       // NN+1
  int* cnt   = offs + NN + 1;                           // NN
  int* curs  = cnt + NN;                                // NN
  int* perm  = curs + NN;                               // NE
  int* srcPos= perm + NE;                               // NE
  int* psum  = srcPos + NE;                             // 256
  int* pofs  = psum + 256;                              // 256

  const int* esrc = ei;
  const int* edst = ei + NE;

  kConvW      <<<(6*16384 + NIN*HID + NN + 255)/256, 256, 0, stream>>>(w1, w2, nw, wtb, wemb2, cnt);
  kHist       <<<(NE + 255)/256, 256, 0, stream>>>(edst, cnt);
  kPartSum    <<<SCAN_B, 256, 0, stream>>>(cnt, psum);
  kScanPart   <<<1, 256, 0, stream>>>(psum, pofs, offs);
  kScanApply  <<<SCAN_B, 256, 0, stream>>>(cnt, pofs, offs, curs);
  kScatterPerm<<<(NE + 255)/256, 256, 0, stream>>>(edst, curs, perm);
  kGatherEA   <<<(NE + 255)/256, 256, 0, stream>>>(perm, esrc, eattr, srcPos, eaPos);
  kNodeInit2  <<<NN/16, 256, 0, stream>>>(x, wemb2, nb, hf);

  for (int l = 0; l < NL; ++l){
    kAgg<<<NB_AGG, 256, 0, stream>>>(hf, eaPos, srcPos, offs,
                                 ew + (size_t)l*EIN*HID, eb + (size_t)l*HID, eps, l,
                                 ab, bnS, bnQ);
    kMlp<<<(NN + BM - 1)/BM, 256, 0, stream>>>(ab, z2,
                                 wtb + (size_t)l*16384, bb1 + (size_t)l*HID,
                                 wtb + (size_t)(3+l)*16384, bb2 + (size_t)l*HID,
                                 bnS, bnQ);
    if (l < NL - 1)
      kBn<<<(NN*64 + 255)/256, 256, 0, stream>>>(z2, bnS, bnQ,
                                 gam + (size_t)l*HID, bet + (size_t)l*HID, hf);
  }

  kPoolHead<<<NG, 192, 0, stream>>>(z2, bnS, bnQ,
                                    gam + (size_t)(NL-1)*HID, bet + (size_t)(NL-1)*HID,
                                    bids, tgt, temb,
                                    h1w, h1b, h2w, h2b, h3w, h3b, out);
}

// Round 18
// 513.896 us; speedup vs baseline: 1.0959x; 1.0142x over previous
//
#include <hip/hip_runtime.h>

#define NN 50000
#define NE 800000
#define NIN 32
#define EIN 16
#define HID 128
#define NL 3
#define NG 256
#define TE 64
#define BM 64        // kMlp row tile
#define SCAN_B 196   // ceil(NN/256)
#define NB_AGG 4096  // kAgg blocks (x4 waves)

typedef unsigned short ushort_t;
typedef __attribute__((ext_vector_type(8))) _Float16 half8;
typedef __attribute__((ext_vector_type(4))) float f32x4;
typedef __attribute__((ext_vector_type(2))) __fp16 h2;

__device__ __forceinline__ unsigned pkf16(float a, float b){
  h2 h = __builtin_amdgcn_cvt_pkrtz(a, b);
  union{ h2 h; unsigned u; } c; c.h = h; return c.u;
}
__device__ __forceinline__ h2 u2h(unsigned u){
  union{ unsigned u; h2 h; } c; c.u = u; return c.h;
}
__device__ __forceinline__ unsigned h2u(h2 h){
  union{ h2 h; unsigned u; } c; c.h = h; return c.u;
}
__device__ __forceinline__ ushort_t f2h(float x){
  union{ __fp16 h; ushort_t u; } c; c.h = (__fp16)x; return c.u;
}
__device__ __forceinline__ float h2f(ushort_t v){
  union{ ushort_t u; __fp16 h; } c; c.u = v; return (float)c.h;
}

// v_pk_fma_f16 with op_sel broadcast of src0 half (zero-cost scalar splat)
#define PKFMA_LO(a, e, w) asm("v_pk_fma_f16 %0, %1, %2, %0 op_sel:[0,0,0] op_sel_hi:[0,1,1]" : "+v"(a) : "v"(e), "v"(w))
#define PKFMA_HI(a, e, w) asm("v_pk_fma_f16 %0, %1, %2, %0 op_sel:[1,0,0] op_sel_hi:[1,1,1]" : "+v"(a) : "v"(e), "v"(w))
// acc(f32) += f16 half of t (single instruction f16->f32 accumulate)
#define FMAMIX_LO(acc, t, one) asm("v_fma_mix_f32 %0, %1, %2, %0 op_sel:[0,0,0] op_sel_hi:[1,0,0]" : "+v"(acc) : "v"(t), "v"(one))
#define FMAMIX_HI(acc, t, one) asm("v_fma_mix_f32 %0, %1, %2, %0 op_sel:[1,0,0] op_sel_hi:[1,0,0]" : "+v"(acc) : "v"(t), "v"(one))

typedef const __attribute__((address_space(1))) unsigned gas_t;
typedef __attribute__((address_space(3))) unsigned las_t;
__device__ __forceinline__ void stage16(const void* g, void* l){
  __builtin_amdgcn_global_load_lds((gas_t*)g, (las_t*)l, 16, 0, 0);
}

// ======================= CSR build (dst-sorted) =======================
__global__ void kHist(const int* __restrict__ dst, int* __restrict__ cnt){
  int e = blockIdx.x*256 + threadIdx.x;
  if (e < NE) atomicAdd(&cnt[dst[e]], 1);
}

__global__ void kPartSum(const int* __restrict__ cnt, int* __restrict__ psum){
  __shared__ int sm[256];
  int b = blockIdx.x, t = threadIdx.x, i = b*256 + t;
  sm[t] = (i < NN) ? cnt[i] : 0;
  __syncthreads();
  for (int o = 128; o > 0; o >>= 1){
    if (t < o) sm[t] += sm[t + o];
    __syncthreads();
  }
  if (t == 0) psum[b] = sm[0];
}

__global__ __launch_bounds__(256) void kScanPart(const int* __restrict__ psum,
                                                 int* __restrict__ pofs, int* __restrict__ offs){
  __shared__ int sm[256];
  int t = threadIdx.x;
  int v = (t < SCAN_B) ? psum[t] : 0;
  sm[t] = v;
  __syncthreads();
  for (int o = 1; o < 256; o <<= 1){
    int x = (t >= o) ? sm[t - o] : 0;
    __syncthreads();
    sm[t] += x;
    __syncthreads();
  }
  if (t < SCAN_B) pofs[t] = sm[t] - v;
  if (t == 255) offs[NN] = sm[255];
}

__global__ void kScanApply(const int* __restrict__ cnt, const int* __restrict__ pofs,
                           int* __restrict__ offs, int* __restrict__ curs){
  __shared__ int sm[256];
  int b = blockIdx.x, t = threadIdx.x, i = b*256 + t;
  int v = (i < NN) ? cnt[i] : 0;
  sm[t] = v;
  __syncthreads();
  for (int o = 1; o < 256; o <<= 1){
    int x = (t >= o) ? sm[t - o] : 0;
    __syncthreads();
    sm[t] += x;
    __syncthreads();
  }
  int ex = sm[t] - v + pofs[b];
  if (i < NN){ offs[i] = ex; curs[i] = ex; }
}

// scatter only the permutation (4B) — minimal scattered-write footprint
__global__ void kScatterPerm(const int* __restrict__ dst, int* __restrict__ curs,
                             int* __restrict__ perm){
  int e = blockIdx.x*256 + threadIdx.x;
  if (e < NE){
    int p = atomicAdd(&curs[dst[e]], 1);
    perm[p] = e;
  }
}

// gather side: coalesced over CSR positions; eattr rows are 64B-aligned full sectors
__global__ void kGatherEA(const int* __restrict__ perm, const int* __restrict__ src,
                          const float* __restrict__ eattr,
                          int* __restrict__ srcPos, unsigned* __restrict__ eaPos){
  int p = blockIdx.x*256 + threadIdx.x;
  if (p >= NE) return;
  int e = perm[p];
  srcPos[p] = src[e];
  const float4* row = (const float4*)(eattr + (size_t)e*EIN);
  float4 v0 = row[0], v1 = row[1], v2 = row[2], v3 = row[3];
  uint4 d0, d1;
  d0.x = pkf16(v0.x, v0.y); d0.y = pkf16(v0.z, v0.w);
  d0.z = pkf16(v1.x, v1.y); d0.w = pkf16(v1.z, v1.w);
  d1.x = pkf16(v2.x, v2.y); d1.y = pkf16(v2.z, v2.w);
  d1.z = pkf16(v3.x, v3.y); d1.w = pkf16(v3.z, v3.w);
  *(uint4*)&eaPos[(size_t)p*8]     = d0;
  *(uint4*)&eaPos[(size_t)p*8 + 4] = d1;
}

// ======================= W -> f16 conversions + stats/cnt zeroing (fused) =======================
__global__ void kConvW(const float* __restrict__ w1, const float* __restrict__ w2,
                       const float* __restrict__ nw,
                       ushort_t* __restrict__ wtb, ushort_t* __restrict__ wemb2,
                       float* __restrict__ bnStats, int* __restrict__ cnt){
  int gid = blockIdx.x*256 + threadIdx.x;
  if (gid < 6*16384){
    int mat = gid >> 14, idx = gid & 16383;
    int k = idx >> 7, n = idx & 127;
    const float* src = (mat < 3) ? (w1 + (size_t)mat*16384) : (w2 + (size_t)(mat-3)*16384);
    wtb[(size_t)mat*16384 + n*128 + (k ^ ((n&7)<<3))] = f2h(src[idx]);
  } else if (gid < 6*16384 + NIN*HID){
    int i = gid - 6*16384;
    wemb2[i] = f2h(nw[i]);
  } else if (gid < 6*16384 + NIN*HID + 2*NL*HID){
    bnStats[gid - (6*16384 + NIN*HID)] = 0.f;   // bnS[NL][HID] then bnQ[NL][HID]
  } else {
    int i = gid - (6*16384 + NIN*HID + 2*NL*HID);
    if (i < NN) cnt[i] = 0;
  }
}

// ======================= node embed -> hf (f16), LDS-staged =======================
__global__ __launch_bounds__(256) void kNodeInit2(const float* __restrict__ x,
    const ushort_t* __restrict__ wemb2, const float* __restrict__ b,
    ushort_t* __restrict__ hf){
  __shared__ float xS[16*33];
  __shared__ __align__(16) ushort_t wS[NIN*HID];
  int t = threadIdx.x;
  int nb = blockIdx.x*16;
  {
    float2 v = *(const float2*)(x + (size_t)nb*NIN + t*2);
    int idx = t*2;
    int r = idx >> 5, k = idx & 31;
    xS[r*33 + k]     = v.x;
    xS[r*33 + k + 1] = v.y;
  }
  stage16((const char*)wemb2 + t*16,        (char*)wS + t*16);
  stage16((const char*)wemb2 + 4096 + t*16, (char*)wS + 4096 + t*16);
  __syncthreads();

  int r = t >> 4, c0 = (t & 15)*8;
  h2 a0, a1, a2, a3;
  a0 = a1 = a2 = a3 = u2h(0u);
  #pragma unroll
  for (int k = 0; k < NIN; ++k){
    float xk = xS[r*33 + k];
    h2 xp = __builtin_amdgcn_cvt_pkrtz(xk, xk);
    uint4 wv = *(const uint4*)&wS[k*HID + c0];
    a0 = __builtin_elementwise_fma(xp, u2h(wv.x), a0);
    a1 = __builtin_elementwise_fma(xp, u2h(wv.y), a1);
    a2 = __builtin_elementwise_fma(xp, u2h(wv.z), a2);
    a3 = __builtin_elementwise_fma(xp, u2h(wv.w), a3);
  }
  float4 bv0 = *(const float4*)&b[c0];
  float4 bv1 = *(const float4*)&b[c0 + 4];
  a0 = a0 + __builtin_amdgcn_cvt_pkrtz(bv0.x, bv0.y);
  a1 = a1 + __builtin_amdgcn_cvt_pkrtz(bv0.z, bv0.w);
  a2 = a2 + __builtin_amdgcn_cvt_pkrtz(bv1.x, bv1.y);
  a3 = a3 + __builtin_amdgcn_cvt_pkrtz(bv1.z, bv1.w);
  uint4 o;
  o.x = h2u(a0); o.y = h2u(a1); o.z = h2u(a2); o.w = h2u(a3);
  *(uint4*)&hf[(size_t)(nb + r)*HID + c0] = o;
}

// ======================= GINE aggregate: LDS-staged batches + op_sel pk_fma =======================
// BN=true: hsrc is raw z2 of previous layer; h = relu(fma(z, sclP, sftP)) computed inline
// (per-lane packed scale/shift precomputed from the previous layer's stats). BN=false: hsrc = hf.
// Writes the FULL MLP input A = (1+eps)*h + sum_e relu(h_src + ea@W + b), f16, PRE-SWIZZLED.
template<bool BN>
__global__ __launch_bounds__(256) void kAgg(
    const ushort_t* __restrict__ hsrc, const unsigned* __restrict__ eaPos,
    const int* __restrict__ srcPos, const int* __restrict__ offs,
    const float* __restrict__ Wl, const float* __restrict__ bl,
    const float* __restrict__ epsArr, int layer,
    const float* __restrict__ bnSp, const float* __restrict__ bnQp,
    const float* __restrict__ gm, const float* __restrict__ bt,
    ushort_t* __restrict__ ab){
  __shared__ unsigned easu[4][16][8];   // [wave][edge][8 u32 = 16 f16 k-values]
  __shared__ int srcsS[4][16];
  int tid = threadIdx.x, lane = tid & 63, wv = tid >> 6;
  int c0 = 2*lane;
  h2 wP[EIN];
  #pragma unroll
  for (int k = 0; k < EIN; ++k)
    wP[k] = __builtin_amdgcn_cvt_pkrtz(Wl[k*HID + c0], Wl[k*HID + c0 + 1]);
  h2 biasP = __builtin_amdgcn_cvt_pkrtz(bl[c0], bl[c0+1]);
  float one = 1.0f;
  float ep1 = 1.f + epsArr[layer];
  h2 sclP = u2h(0u), sftP = u2h(0u);
  if (BN){
    float m0 = bnSp[c0]*(1.f/NN),   m1 = bnSp[c0+1]*(1.f/NN);
    float v0 = bnQp[c0]*(1.f/NN) - m0*m0, v1 = bnQp[c0+1]*(1.f/NN) - m1*m1;
    float s0 = rsqrtf(v0 + 1e-5f)*gm[c0], s1 = rsqrtf(v1 + 1e-5f)*gm[c0+1];
    sclP = __builtin_amdgcn_cvt_pkrtz(s0, s1);
    sftP = __builtin_amdgcn_cvt_pkrtz(bt[c0] - m0*s0, bt[c0+1] - m1*s1);
  }

  for (int n = blockIdx.x*4 + wv; n < NN; n += NB_AGG*4){
    int s0 = offs[n], s1 = offs[n+1];
    float acc0 = 0.f, acc1 = 0.f;

    auto BODY = [&](int i, unsigned hs){
      const uint4* A = (const uint4*)&easu[wv][i][0];
      uint4 e0 = A[0], e1 = A[1];
      h2 a = biasP;
      PKFMA_LO(a, e0.x, wP[0]);  PKFMA_HI(a, e0.x, wP[1]);
      PKFMA_LO(a, e0.y, wP[2]);  PKFMA_HI(a, e0.y, wP[3]);
      PKFMA_LO(a, e0.z, wP[4]);  PKFMA_HI(a, e0.z, wP[5]);
      PKFMA_LO(a, e0.w, wP[6]);  PKFMA_HI(a, e0.w, wP[7]);
      PKFMA_LO(a, e1.x, wP[8]);  PKFMA_HI(a, e1.x, wP[9]);
      PKFMA_LO(a, e1.y, wP[10]); PKFMA_HI(a, e1.y, wP[11]);
      PKFMA_LO(a, e1.z, wP[12]); PKFMA_HI(a, e1.z, wP[13]);
      PKFMA_LO(a, e1.w, wP[14]); PKFMA_HI(a, e1.w, wP[15]);
      h2 zz; zz[0] = (__fp16)0.f; zz[1] = (__fp16)0.f;
      h2 hvv = u2h(hs);
      if (BN){
        hvv = __builtin_elementwise_fma(hvv, sclP, sftP);
        hvv = __builtin_elementwise_max(hvv, zz);
      }
      h2 t = a + hvv;
      t = __builtin_elementwise_max(t, zz);
      FMAMIX_LO(acc0, t, one);
      FMAMIX_HI(acc1, t, one);
    };

    for (int j = s0; j < s1; j += 16){
      int cnt = min(16, s1 - j);
      if (lane < cnt) srcsS[wv][lane] = srcPos[j + lane];
      if (lane < 4*cnt){
        int r = lane >> 2, part = lane & 3;
        *(uint2*)&easu[wv][r][part*2] = *(const uint2*)&eaPos[(size_t)(j + r)*8 + part*2];
      }
      asm volatile("s_waitcnt lgkmcnt(0)" ::: "memory");
      if (cnt == 16){
        unsigned hsv[16];
        #pragma unroll
        for (int i = 0; i < 16; ++i)
          hsv[i] = *(const unsigned*)&hsrc[(size_t)srcsS[wv][i]*HID + c0];
        #pragma unroll
        for (int i = 0; i < 16; ++i) BODY(i, hsv[i]);
      } else {
        for (int i = 0; i < cnt; ++i){
          unsigned hs = *(const unsigned*)&hsrc[(size_t)srcsS[wv][i]*HID + c0];
          BODY(i, hs);
        }
      }
      asm volatile("s_waitcnt lgkmcnt(0)" ::: "memory");  // easu reads done before overwrite
    }
    unsigned hw = *(const unsigned*)&hsrc[(size_t)n*HID + c0];
    h2 hv = u2h(hw);
    if (BN){
      h2 zz; zz[0] = (__fp16)0.f; zz[1] = (__fp16)0.f;
      hv = __builtin_elementwise_fma(hv, sclP, sftP);
      hv = __builtin_elementwise_max(hv, zz);
    }
    float z0 = fmaf(ep1, (float)hv[0], acc0);
    float z1 = fmaf(ep1, (float)hv[1], acc1);
    *(unsigned*)&ab[(size_t)n*HID + (c0 ^ ((n & 7) << 3))] = pkf16(z0, z1);
  }
}

// ======================= fused MLP via MFMA (f16): z2 = relu(A@W1+b1)@W2+b2 =======================
// A staged directly via global_load_lds (kAgg pre-swizzled it). z2 out f16 + BN partial stats.
__global__ __launch_bounds__(256, 1) void kMlp(
    const ushort_t* __restrict__ ab, ushort_t* __restrict__ z2,
    const ushort_t* __restrict__ w1t, const float* __restrict__ b1,
    const ushort_t* __restrict__ w2t, const float* __restrict__ b2,
    float* __restrict__ bnS, float* __restrict__ bnQ){
  __shared__ __align__(16) ushort_t As[BM*128];
  __shared__ __align__(16) ushort_t Bs[128*128];
  __shared__ float red[256];
  int tid  = threadIdx.x;
  int lane = tid & 63;
  int w    = tid >> 6;
  int ln   = tid & 15;
  int q    = (tid >> 4) & 3;
  int rbase = blockIdx.x * BM;
  int m0 = (w >> 1) * 32;
  int wc = (w & 1) * 64;

  const char* gA = (const char*)(ab + (size_t)rbase * HID);
  #pragma unroll
  for (int it = 0; it < 4; ++it)
    stage16(gA + (w*4096 + it*1024 + lane*16), (char*)As + (w*4096 + it*1024));
  const char* gB1 = (const char*)w1t;
  #pragma unroll
  for (int it = 0; it < 8; ++it)
    stage16(gB1 + (w*8192 + it*1024 + lane*16), (char*)Bs + (w*8192 + it*1024));
  __syncthreads();

  f32x4 acc[2][4];
  #pragma unroll
  for (int i = 0; i < 2; ++i)
    #pragma unroll
    for (int j = 0; j < 4; ++j) acc[i][j] = (f32x4)0.f;

  #pragma unroll
  for (int kk = 0; kk < 4; ++kk){
    int kb = kk*32 + q*8;
    half8 af[2], bf[4];
    #pragma unroll
    for (int i = 0; i < 2; ++i){
      int m = m0 + 16*i + ln;
      af[i] = *(const half8*)&As[m*128 + (kb ^ ((m&7)<<3))];
    }
    #pragma unroll
    for (int j = 0; j < 4; ++j){
      int nn = wc + 16*j + ln;
      bf[j] = *(const half8*)&Bs[nn*128 + (kb ^ ((nn&7)<<3))];
    }
    #pragma unroll
    for (int i = 0; i < 2; ++i)
      #pragma unroll
      for (int j = 0; j < 4; ++j)
        acc[i][j] = __builtin_amdgcn_mfma_f32_16x16x32_f16(af[i], bf[j], acc[i][j], 0, 0, 0);
  }
  __syncthreads();

  const char* gB2 = (const char*)w2t;
  #pragma unroll
  for (int it = 0; it < 8; ++it)
    stage16(gB2 + (w*8192 + it*1024 + lane*16), (char*)Bs + (w*8192 + it*1024));
  {
    float b1v[4];
    #pragma unroll
    for (int j = 0; j < 4; ++j) b1v[j] = b1[wc + 16*j + ln];
    #pragma unroll
    for (int i = 0; i < 2; ++i){
      #pragma unroll
      for (int j = 0; j < 4; ++j){
        int kc = wc + 16*j + ln;
        #pragma unroll
        for (int r = 0; r < 4; ++r){
          int m = m0 + 16*i + 4*q + r;
          As[m*128 + (kc ^ ((m&7)<<3))] = f2h(fmaxf(acc[i][j][r] + b1v[j], 0.f));
        }
      }
    }
  }
  #pragma unroll
  for (int i = 0; i < 2; ++i)
    #pragma unroll
    for (int j = 0; j < 4; ++j) acc[i][j] = (f32x4)0.f;
  __syncthreads();

  #pragma unroll
  for (int kk = 0; kk < 4; ++kk){
    int kb = kk*32 + q*8;
    half8 af[2], bf[4];
    #pragma unroll
    for (int i = 0; i < 2; ++i){
      int m = m0 + 16*i + ln;
      af[i] = *(const half8*)&As[m*128 + (kb ^ ((m&7)<<3))];
    }
    #pragma unroll
    for (int j = 0; j < 4; ++j){
      int nn = wc + 16*j + ln;
      bf[j] = *(const half8*)&Bs[nn*128 + (kb ^ ((nn&7)<<3))];
    }
    #pragma unroll
    for (int i = 0; i < 2; ++i)
      #pragma unroll
      for (int j = 0; j < 4; ++j)
        acc[i][j] = __builtin_amdgcn_mfma_f32_16x16x32_f16(af[i], bf[j], acc[i][j], 0, 0, 0);
  }

  float b2v[4];
  #pragma unroll
  for (int j = 0; j < 4; ++j) b2v[j] = b2[wc + 16*j + ln];
  float ps[4], pq[4];
  #pragma unroll
  for (int j = 0; j < 4; ++j){ ps[j] = 0.f; pq[j] = 0.f; }
  #pragma unroll
  for (int i = 0; i < 2; ++i){
    #pragma unroll
    for (int r = 0; r < 4; ++r){
      int rg = rbase + m0 + 16*i + 4*q + r;
      if (rg < NN){
        #pragma unroll
        for (int j = 0; j < 4; ++j){
          float v = acc[i][j][r] + b2v[j];
          z2[(size_t)rg*HID + wc + 16*j + ln] = f2h(v);
          ps[j] += v; pq[j] += v*v;
        }
      }
    }
  }
  red[tid] = 0.f;
  if (tid < 128) red[128 + tid] = 0.f;
  __syncthreads();
  #pragma unroll
  for (int j = 0; j < 4; ++j){
    int c = wc + 16*j + ln;
    atomicAdd(&red[c], ps[j]);
    atomicAdd(&red[128 + c], pq[j]);
  }
  __syncthreads();
  if (tid < 128){
    atomicAdd(&bnS[tid], red[tid]);
    atomicAdd(&bnQ[tid], red[128 + tid]);
  }
}

// ======================= fused pool + head (last-layer BN applied inline from z2) =======================
__global__ __launch_bounds__(192) void kPoolHead(const ushort_t* __restrict__ z2,
    const float* __restrict__ bnS, const float* __restrict__ bnQ,
    const float* __restrict__ gamma, const float* __restrict__ beta,
    const int* __restrict__ bid, const int* __restrict__ tidx,
    const float* __restrict__ temb,
    const float* __restrict__ w1, const float* __restrict__ b1,
    const float* __restrict__ w2, const float* __restrict__ b2,
    const float* __restrict__ w3, const float* __restrict__ b3,
    float* __restrict__ out){
  __shared__ float gv[192];
  __shared__ float t1[128];
  __shared__ float t2[64];
  int b = blockIdx.x, t = threadIdx.x;
  int lo = 0, hi = NN;
  while (lo < hi){ int m = (lo + hi) >> 1; if (bid[m] < b) lo = m + 1; else hi = m; }
  int s = lo;
  lo = 0; hi = NN;
  while (lo < hi){ int m = (lo + hi) >> 1; if (bid[m] < b + 1) lo = m + 1; else hi = m; }
  int e = lo;
  if (t < HID){
    float mean = bnS[t] * (1.f/NN);
    float var  = bnQ[t] * (1.f/NN) - mean*mean;
    float scl  = rsqrtf(var + 1e-5f) * gamma[t];
    float sft  = beta[t] - mean*scl;
    float acc = 0.f;
    for (int n = s; n < e; ++n)
      acc += fmaxf(fmaf(h2f(z2[(size_t)n*HID + t]), scl, sft), 0.f);
    gv[t] = acc;
  } else {
    gv[t] = temb[tidx[b]*TE + (t - HID)];
  }
  __syncthreads();
  float acc = b1[t & 127];
  if (t < HID){
    for (int k = 0; k < 192; ++k) acc = fmaf(gv[k], w1[k*HID + t], acc);
    t1[t] = fmaxf(acc, 0.f);
  }
  __syncthreads();
  if (t < 64){
    float a2 = b2[t];
    for (int k = 0; k < 128; ++k) a2 = fmaf(t1[k], w2[k*64 + t], a2);
    t2[t] = fmaxf(a2, 0.f);
  }
  __syncthreads();
  if (t == 0){
    float sv = b3[0];
    for (int k = 0; k < 64; ++k) sv = fmaf(t2[k], w3[k], sv);
    out[b] = sv;
  }
}

// ======================= launch =======================
extern "C" void kernel_launch(void* const* d_in, const int* in_sizes, int n_in,
                              void* d_out, int out_size, void* d_ws, size_t ws_size,
                              hipStream_t stream){
  const float* x     = (const float*)d_in[0];
  const int*   ei    = (const int*)  d_in[1];
  const float* eattr = (const float*)d_in[2];
  const int*   bids  = (const int*)  d_in[3];
  const int*   tgt   = (const int*)  d_in[4];
  const float* nw    = (const float*)d_in[5];
  const float* nb    = (const float*)d_in[6];
  const float* eps   = (const float*)d_in[7];
  const float* ew    = (const float*)d_in[8];
  const float* eb    = (const float*)d_in[9];
  const float* w1    = (const float*)d_in[10];
  const float* bb1   = (const float*)d_in[11];
  const float* w2    = (const float*)d_in[12];
  const float* bb2   = (const float*)d_in[13];
  const float* gam   = (const float*)d_in[14];
  const float* bet   = (const float*)d_in[15];
  const float* temb  = (const float*)d_in[16];
  const float* h1w   = (const float*)d_in[17];
  const float* h1b   = (const float*)d_in[18];
  const float* h2w   = (const float*)d_in[19];
  const float* h2b   = (const float*)d_in[20];
  const float* h3w   = (const float*)d_in[21];
  const float* h3b   = (const float*)d_in[22];
  float* out = (float*)d_out;

  ushort_t* ab   = (ushort_t*)d_ws;                     // (NN+64)*128
  ushort_t* wtb  = ab + (size_t)(NN + 64)*HID;          // 6*16384
  ushort_t* wemb2= wtb + (size_t)6*16384;               // NIN*HID
  ushort_t* hf   = wemb2 + (size_t)NIN*HID;             // (NN+64)*128
  ushort_t* z2   = hf + (size_t)(NN + 64)*HID;          // NN*128 (f16)
  unsigned* eaPos = (unsigned*)(z2 + (size_t)NN*HID);   // NE*8
  float* bnS = (float*)(eaPos + (size_t)NE*8);          // NL*128
  float* bnQ = bnS + NL*HID;                            // NL*128
  int* offs  = (int*)(bnQ + NL*HID);                    // NN+1
  int* cnt   = offs + NN + 1;                           // NN
  int* curs  = cnt + NN;                                // NN
  int* perm  = curs + NN;                               // NE
  int* srcPos= perm + NE;                               // NE
  int* psum  = srcPos + NE;                             // 256
  int* pofs  = psum + 256;                              // 256

  const int* esrc = ei;
  const int* edst = ei + NE;

  kConvW      <<<(6*16384 + NIN*HID + 2*NL*HID + NN + 255)/256, 256, 0, stream>>>(w1, w2, nw, wtb, wemb2, bnS, cnt);
  kHist       <<<(NE + 255)/256, 256, 0, stream>>>(edst, cnt);
  kPartSum    <<<SCAN_B, 256, 0, stream>>>(cnt, psum);
  kScanPart   <<<1, 256, 0, stream>>>(psum, pofs, offs);
  kScanApply  <<<SCAN_B, 256, 0, stream>>>(cnt, pofs, offs, curs);
  kScatterPerm<<<(NE + 255)/256, 256, 0, stream>>>(edst, curs, perm);
  kGatherEA   <<<(NE + 255)/256, 256, 0, stream>>>(perm, esrc, eattr, srcPos, eaPos);
  kNodeInit2  <<<NN/16, 256, 0, stream>>>(x, wemb2, nb, hf);

  for (int l = 0; l < NL; ++l){
    if (l == 0){
      kAgg<false><<<NB_AGG, 256, 0, stream>>>(hf, eaPos, srcPos, offs,
                                   ew, eb, eps, 0,
                                   bnS, bnQ, gam, bet, ab);
    } else {
      kAgg<true><<<NB_AGG, 256, 0, stream>>>(z2, eaPos, srcPos, offs,
                                   ew + (size_t)l*EIN*HID, eb + (size_t)l*HID, eps, l,
                                   bnS + (size_t)(l-1)*HID, bnQ + (size_t)(l-1)*HID,
                                   gam + (size_t)(l-1)*HID, bet + (size_t)(l-1)*HID, ab);
    }
    kMlp<<<(NN + BM - 1)/BM, 256, 0, stream>>>(ab, z2,
                                 wtb + (size_t)l*16384, bb1 + (size_t)l*HID,
                                 wtb + (size_t)(3+l)*16384, bb2 + (size_t)l*HID,
                                 bnS + (size_t)l*HID, bnQ + (size_t)l*HID);
  }

  kPoolHead<<<NG, 192, 0, stream>>>(z2, bnS + (size_t)(NL-1)*HID, bnQ + (size_t)(NL-1)*HID,
                                    gam + (size_t)(NL-1)*HID, bet + (size_t)(NL-1)*HID,
                                    bids, tgt, temb,
                                    h1w, h1b, h2w, h2b, h3w, h3b, out);
}

// Round 19
// 453.194 us; speedup vs baseline: 1.2427x; 1.1339x over previous
//
#include <hip/hip_runtime.h>

#define NN 50000
#define NE 800000
#define NIN 32
#define EIN 16
#define HID 128
#define NL 3
#define NG 256
#define TE 64
#define BM2 128      // kMlp row tile
#define SCAN_B 196   // ceil(NN/256)
#define NB_AGG 4096  // kAgg blocks (x4 waves)

typedef unsigned short ushort_t;
typedef __attribute__((ext_vector_type(8))) _Float16 half8;
typedef __attribute__((ext_vector_type(4))) float f32x4;
typedef __attribute__((ext_vector_type(2))) __fp16 h2;

__device__ __forceinline__ unsigned pkf16(float a, float b){
  h2 h = __builtin_amdgcn_cvt_pkrtz(a, b);
  union{ h2 h; unsigned u; } c; c.h = h; return c.u;
}
__device__ __forceinline__ h2 u2h(unsigned u){
  union{ unsigned u; h2 h; } c; c.u = u; return c.h;
}
__device__ __forceinline__ unsigned h2u(h2 h){
  union{ h2 h; unsigned u; } c; c.h = h; return c.u;
}
__device__ __forceinline__ ushort_t f2h(float x){
  union{ __fp16 h; ushort_t u; } c; c.h = (__fp16)x; return c.u;
}
__device__ __forceinline__ float h2f(ushort_t v){
  union{ ushort_t u; __fp16 h; } c; c.u = v; return (float)c.h;
}

// v_pk_fma_f16 with op_sel broadcast of src0 half (zero-cost scalar splat)
#define PKFMA_LO(a, e, w) asm("v_pk_fma_f16 %0, %1, %2, %0 op_sel:[0,0,0] op_sel_hi:[0,1,1]" : "+v"(a) : "v"(e), "v"(w))
#define PKFMA_HI(a, e, w) asm("v_pk_fma_f16 %0, %1, %2, %0 op_sel:[1,0,0] op_sel_hi:[1,1,1]" : "+v"(a) : "v"(e), "v"(w))
// acc(f32) += f16 half of t (single instruction f16->f32 accumulate)
#define FMAMIX_LO(acc, t, one) asm("v_fma_mix_f32 %0, %1, %2, %0 op_sel:[0,0,0] op_sel_hi:[1,0,0]" : "+v"(acc) : "v"(t), "v"(one))
#define FMAMIX_HI(acc, t, one) asm("v_fma_mix_f32 %0, %1, %2, %0 op_sel:[1,0,0] op_sel_hi:[1,0,0]" : "+v"(acc) : "v"(t), "v"(one))

typedef const __attribute__((address_space(1))) unsigned gas_t;
typedef __attribute__((address_space(3))) unsigned las_t;
__device__ __forceinline__ void stage16(const void* g, void* l){
  __builtin_amdgcn_global_load_lds((gas_t*)g, (las_t*)l, 16, 0, 0);
}

// ======================= CSR build (dst-sorted) =======================
__global__ void kHist(const int* __restrict__ dst, int* __restrict__ cnt){
  int e = blockIdx.x*256 + threadIdx.x;
  if (e < NE) atomicAdd(&cnt[dst[e]], 1);
}

__global__ void kPartSum(const int* __restrict__ cnt, int* __restrict__ psum){
  __shared__ int sm[256];
  int b = blockIdx.x, t = threadIdx.x, i = b*256 + t;
  sm[t] = (i < NN) ? cnt[i] : 0;
  __syncthreads();
  for (int o = 128; o > 0; o >>= 1){
    if (t < o) sm[t] += sm[t + o];
    __syncthreads();
  }
  if (t == 0) psum[b] = sm[0];
}

__global__ __launch_bounds__(256) void kScanPart(const int* __restrict__ psum,
                                                 int* __restrict__ pofs, int* __restrict__ offs){
  __shared__ int sm[256];
  int t = threadIdx.x;
  int v = (t < SCAN_B) ? psum[t] : 0;
  sm[t] = v;
  __syncthreads();
  for (int o = 1; o < 256; o <<= 1){
    int x = (t >= o) ? sm[t - o] : 0;
    __syncthreads();
    sm[t] += x;
    __syncthreads();
  }
  if (t < SCAN_B) pofs[t] = sm[t] - v;
  if (t == 255) offs[NN] = sm[255];
}

__global__ void kScanApply(const int* __restrict__ cnt, const int* __restrict__ pofs,
                           int* __restrict__ offs, int* __restrict__ curs){
  __shared__ int sm[256];
  int b = blockIdx.x, t = threadIdx.x, i = b*256 + t;
  int v = (i < NN) ? cnt[i] : 0;
  sm[t] = v;
  __syncthreads();
  for (int o = 1; o < 256; o <<= 1){
    int x = (t >= o) ? sm[t - o] : 0;
    __syncthreads();
    sm[t] += x;
    __syncthreads();
  }
  int ex = sm[t] - v + pofs[b];
  if (i < NN){ offs[i] = ex; curs[i] = ex; }
}

// scatter only the permutation (4B) — minimal scattered-write footprint
__global__ void kScatterPerm(const int* __restrict__ dst, int* __restrict__ curs,
                             int* __restrict__ perm){
  int e = blockIdx.x*256 + threadIdx.x;
  if (e < NE){
    int p = atomicAdd(&curs[dst[e]], 1);
    perm[p] = e;
  }
}

// gather side: coalesced over CSR positions; eattr rows are 64B-aligned full sectors
__global__ void kGatherEA(const int* __restrict__ perm, const int* __restrict__ src,
                          const float* __restrict__ eattr,
                          int* __restrict__ srcPos, unsigned* __restrict__ eaPos){
  int p = blockIdx.x*256 + threadIdx.x;
  if (p >= NE) return;
  int e = perm[p];
  srcPos[p] = src[e];
  const float4* row = (const float4*)(eattr + (size_t)e*EIN);
  float4 v0 = row[0], v1 = row[1], v2 = row[2], v3 = row[3];
  uint4 d0, d1;
  d0.x = pkf16(v0.x, v0.y); d0.y = pkf16(v0.z, v0.w);
  d0.z = pkf16(v1.x, v1.y); d0.w = pkf16(v1.z, v1.w);
  d1.x = pkf16(v2.x, v2.y); d1.y = pkf16(v2.z, v2.w);
  d1.z = pkf16(v3.x, v3.y); d1.w = pkf16(v3.z, v3.w);
  *(uint4*)&eaPos[(size_t)p*8]     = d0;
  *(uint4*)&eaPos[(size_t)p*8 + 4] = d1;
}

// ======================= W -> f16 conversions + stats/cnt zeroing (fused) =======================
__global__ void kConvW(const float* __restrict__ w1, const float* __restrict__ w2,
                       const float* __restrict__ nw,
                       ushort_t* __restrict__ wtb, ushort_t* __restrict__ wemb2,
                       float* __restrict__ bnStats, int* __restrict__ cnt){
  int gid = blockIdx.x*256 + threadIdx.x;
  if (gid < 6*16384){
    int mat = gid >> 14, idx = gid & 16383;
    int k = idx >> 7, n = idx & 127;
    const float* src = (mat < 3) ? (w1 + (size_t)mat*16384) : (w2 + (size_t)(mat-3)*16384);
    wtb[(size_t)mat*16384 + n*128 + (k ^ ((n&7)<<3))] = f2h(src[idx]);
  } else if (gid < 6*16384 + NIN*HID){
    int i = gid - 6*16384;
    wemb2[i] = f2h(nw[i]);
  } else if (gid < 6*16384 + NIN*HID + 2*NL*HID){
    bnStats[gid - (6*16384 + NIN*HID)] = 0.f;   // bnS[NL][HID] then bnQ[NL][HID]
  } else {
    int i = gid - (6*16384 + NIN*HID + 2*NL*HID);
    if (i < NN) cnt[i] = 0;
  }
}

// ======================= node embed -> hf (f16), LDS-staged =======================
__global__ __launch_bounds__(256) void kNodeInit2(const float* __restrict__ x,
    const ushort_t* __restrict__ wemb2, const float* __restrict__ b,
    ushort_t* __restrict__ hf){
  __shared__ float xS[16*33];
  __shared__ __align__(16) ushort_t wS[NIN*HID];
  int t = threadIdx.x;
  int nb = blockIdx.x*16;
  {
    float2 v = *(const float2*)(x + (size_t)nb*NIN + t*2);
    int idx = t*2;
    int r = idx >> 5, k = idx & 31;
    xS[r*33 + k]     = v.x;
    xS[r*33 + k + 1] = v.y;
  }
  stage16((const char*)wemb2 + t*16,        (char*)wS + t*16);
  stage16((const char*)wemb2 + 4096 + t*16, (char*)wS + 4096 + t*16);
  __syncthreads();

  int r = t >> 4, c0 = (t & 15)*8;
  h2 a0, a1, a2, a3;
  a0 = a1 = a2 = a3 = u2h(0u);
  #pragma unroll
  for (int k = 0; k < NIN; ++k){
    float xk = xS[r*33 + k];
    h2 xp = __builtin_amdgcn_cvt_pkrtz(xk, xk);
    uint4 wv = *(const uint4*)&wS[k*HID + c0];
    a0 = __builtin_elementwise_fma(xp, u2h(wv.x), a0);
    a1 = __builtin_elementwise_fma(xp, u2h(wv.y), a1);
    a2 = __builtin_elementwise_fma(xp, u2h(wv.z), a2);
    a3 = __builtin_elementwise_fma(xp, u2h(wv.w), a3);
  }
  float4 bv0 = *(const float4*)&b[c0];
  float4 bv1 = *(const float4*)&b[c0 + 4];
  a0 = a0 + __builtin_amdgcn_cvt_pkrtz(bv0.x, bv0.y);
  a1 = a1 + __builtin_amdgcn_cvt_pkrtz(bv0.z, bv0.w);
  a2 = a2 + __builtin_amdgcn_cvt_pkrtz(bv1.x, bv1.y);
  a3 = a3 + __builtin_amdgcn_cvt_pkrtz(bv1.z, bv1.w);
  uint4 o;
  o.x = h2u(a0); o.y = h2u(a1); o.z = h2u(a2); o.w = h2u(a3);
  *(uint4*)&hf[(size_t)(nb + r)*HID + c0] = o;
}

// ======================= GINE aggregate: LDS-staged batches + op_sel pk_fma =======================
// BN=true: hsrc is raw z2 of previous layer; h = relu(fma(z, sclP, sftP)) computed inline.
// Writes the FULL MLP input A = (1+eps)*h + sum_e relu(h_src + ea@W + b), f16, PRE-SWIZZLED.
template<bool BN>
__global__ __launch_bounds__(256, 8) void kAgg(
    const ushort_t* __restrict__ hsrc, const unsigned* __restrict__ eaPos,
    const int* __restrict__ srcPos, const int* __restrict__ offs,
    const float* __restrict__ Wl, const float* __restrict__ bl,
    const float* __restrict__ epsArr, int layer,
    const float* __restrict__ bnSp, const float* __restrict__ bnQp,
    const float* __restrict__ gm, const float* __restrict__ bt,
    ushort_t* __restrict__ ab){
  __shared__ unsigned easu[4][16][8];   // [wave][edge][8 u32 = 16 f16 k-values]
  __shared__ int srcsS[4][16];
  int tid = threadIdx.x, lane = tid & 63, wv = tid >> 6;
  int c0 = 2*lane;
  h2 wP[EIN];
  #pragma unroll
  for (int k = 0; k < EIN; ++k)
    wP[k] = __builtin_amdgcn_cvt_pkrtz(Wl[k*HID + c0], Wl[k*HID + c0 + 1]);
  h2 biasP = __builtin_amdgcn_cvt_pkrtz(bl[c0], bl[c0+1]);
  float one = 1.0f;
  float ep1 = 1.f + epsArr[layer];
  h2 sclP = u2h(0u), sftP = u2h(0u);
  if (BN){
    float m0 = bnSp[c0]*(1.f/NN),   m1 = bnSp[c0+1]*(1.f/NN);
    float v0 = bnQp[c0]*(1.f/NN) - m0*m0, v1 = bnQp[c0+1]*(1.f/NN) - m1*m1;
    float s0 = rsqrtf(v0 + 1e-5f)*gm[c0], s1 = rsqrtf(v1 + 1e-5f)*gm[c0+1];
    sclP = __builtin_amdgcn_cvt_pkrtz(s0, s1);
    sftP = __builtin_amdgcn_cvt_pkrtz(bt[c0] - m0*s0, bt[c0+1] - m1*s1);
  }

  for (int n = blockIdx.x*4 + wv; n < NN; n += NB_AGG*4){
    int s0 = offs[n], s1 = offs[n+1];
    float acc0 = 0.f, acc1 = 0.f;

    auto BODY = [&](int i, unsigned hs){
      const uint4* A = (const uint4*)&easu[wv][i][0];
      uint4 e0 = A[0], e1 = A[1];
      h2 a = biasP;
      PKFMA_LO(a, e0.x, wP[0]);  PKFMA_HI(a, e0.x, wP[1]);
      PKFMA_LO(a, e0.y, wP[2]);  PKFMA_HI(a, e0.y, wP[3]);
      PKFMA_LO(a, e0.z, wP[4]);  PKFMA_HI(a, e0.z, wP[5]);
      PKFMA_LO(a, e0.w, wP[6]);  PKFMA_HI(a, e0.w, wP[7]);
      PKFMA_LO(a, e1.x, wP[8]);  PKFMA_HI(a, e1.x, wP[9]);
      PKFMA_LO(a, e1.y, wP[10]); PKFMA_HI(a, e1.y, wP[11]);
      PKFMA_LO(a, e1.z, wP[12]); PKFMA_HI(a, e1.z, wP[13]);
      PKFMA_LO(a, e1.w, wP[14]); PKFMA_HI(a, e1.w, wP[15]);
      h2 zz; zz[0] = (__fp16)0.f; zz[1] = (__fp16)0.f;
      h2 hvv = u2h(hs);
      if (BN){
        hvv = __builtin_elementwise_fma(hvv, sclP, sftP);
        hvv = __builtin_elementwise_max(hvv, zz);
      }
      h2 t = a + hvv;
      t = __builtin_elementwise_max(t, zz);
      FMAMIX_LO(acc0, t, one);
      FMAMIX_HI(acc1, t, one);
    };

    for (int j = s0; j < s1; j += 16){
      int cnt = min(16, s1 - j);
      if (lane < cnt) srcsS[wv][lane] = srcPos[j + lane];
      if (lane < 4*cnt){
        int r = lane >> 2, part = lane & 3;
        *(uint2*)&easu[wv][r][part*2] = *(const uint2*)&eaPos[(size_t)(j + r)*8 + part*2];
      }
      asm volatile("s_waitcnt lgkmcnt(0)" ::: "memory");
      if (cnt == 16){
        unsigned hsv[16];
        #pragma unroll
        for (int i = 0; i < 16; ++i)
          hsv[i] = *(const unsigned*)&hsrc[(size_t)srcsS[wv][i]*HID + c0];
        #pragma unroll
        for (int i = 0; i < 16; ++i) BODY(i, hsv[i]);
      } else {
        for (int i = 0; i < cnt; ++i){
          unsigned hs = *(const unsigned*)&hsrc[(size_t)srcsS[wv][i]*HID + c0];
          BODY(i, hs);
        }
      }
      asm volatile("s_waitcnt lgkmcnt(0)" ::: "memory");  // easu reads done before overwrite
    }
    unsigned hw = *(const unsigned*)&hsrc[(size_t)n*HID + c0];
    h2 hv = u2h(hw);
    if (BN){
      h2 zz; zz[0] = (__fp16)0.f; zz[1] = (__fp16)0.f;
      hv = __builtin_elementwise_fma(hv, sclP, sftP);
      hv = __builtin_elementwise_max(hv, zz);
    }
    float z0 = fmaf(ep1, (float)hv[0], acc0);
    float z1 = fmaf(ep1, (float)hv[1], acc1);
    *(unsigned*)&ab[(size_t)n*HID + (c0 ^ ((n & 7) << 3))] = pkf16(z0, z1);
  }
}

// ======================= fused MLP via MFMA (f16), BM2=128: z2 = relu(A@W1+b1)@W2+b2 =======================
// A staged directly via global_load_lds (kAgg pre-swizzled it). z2 out f16 + BN partial stats.
__global__ __launch_bounds__(256, 2) void kMlp(
    const ushort_t* __restrict__ ab, ushort_t* __restrict__ z2,
    const ushort_t* __restrict__ w1t, const float* __restrict__ b1,
    const ushort_t* __restrict__ w2t, const float* __restrict__ b2,
    float* __restrict__ bnS, float* __restrict__ bnQ){
  __shared__ __align__(16) ushort_t As[BM2*128];   // 32KB
  __shared__ __align__(16) ushort_t Bs[128*128];   // 32KB
  __shared__ float red[256];
  int tid  = threadIdx.x;
  int lane = tid & 63;
  int w    = tid >> 6;
  int ln   = tid & 15;
  int q    = (tid >> 4) & 3;
  int rbase = blockIdx.x * BM2;
  int m0 = (w >> 1) * 64;    // 2x2 waves, 64x64 output each
  int wc = (w & 1) * 64;

  const char* gA = (const char*)(ab + (size_t)rbase * HID);
  #pragma unroll
  for (int it = 0; it < 8; ++it)
    stage16(gA + (it*4096 + tid*16), (char*)As + (it*4096 + tid*16));
  const char* gB1 = (const char*)w1t;
  #pragma unroll
  for (int it = 0; it < 8; ++it)
    stage16(gB1 + (w*8192 + it*1024 + lane*16), (char*)Bs + (w*8192 + it*1024));
  __syncthreads();

  f32x4 acc[4][4];
  #pragma unroll
  for (int i = 0; i < 4; ++i)
    #pragma unroll
    for (int j = 0; j < 4; ++j) acc[i][j] = (f32x4)0.f;

  #pragma unroll
  for (int kk = 0; kk < 4; ++kk){
    int kb = kk*32 + q*8;
    half8 af[4], bf[4];
    #pragma unroll
    for (int i = 0; i < 4; ++i){
      int m = m0 + 16*i + ln;
      af[i] = *(const half8*)&As[m*128 + (kb ^ ((m&7)<<3))];
    }
    #pragma unroll
    for (int j = 0; j < 4; ++j){
      int nn = wc + 16*j + ln;
      bf[j] = *(const half8*)&Bs[nn*128 + (kb ^ ((nn&7)<<3))];
    }
    #pragma unroll
    for (int i = 0; i < 4; ++i)
      #pragma unroll
      for (int j = 0; j < 4; ++j)
        acc[i][j] = __builtin_amdgcn_mfma_f32_16x16x32_f16(af[i], bf[j], acc[i][j], 0, 0, 0);
  }
  __syncthreads();

  const char* gB2 = (const char*)w2t;
  #pragma unroll
  for (int it = 0; it < 8; ++it)
    stage16(gB2 + (w*8192 + it*1024 + lane*16), (char*)Bs + (w*8192 + it*1024));
  {
    float b1v[4];
    #pragma unroll
    for (int j = 0; j < 4; ++j) b1v[j] = b1[wc + 16*j + ln];
    #pragma unroll
    for (int i = 0; i < 4; ++i){
      #pragma unroll
      for (int j = 0; j < 4; ++j){
        int kc = wc + 16*j + ln;
        #pragma unroll
        for (int r = 0; r < 4; ++r){
          int m = m0 + 16*i + 4*q + r;
          As[m*128 + (kc ^ ((m&7)<<3))] = f2h(fmaxf(acc[i][j][r] + b1v[j], 0.f));
        }
      }
    }
  }
  #pragma unroll
  for (int i = 0; i < 4; ++i)
    #pragma unroll
    for (int j = 0; j < 4; ++j) acc[i][j] = (f32x4)0.f;
  __syncthreads();

  #pragma unroll
  for (int kk = 0; kk < 4; ++kk){
    int kb = kk*32 + q*8;
    half8 af[4], bf[4];
    #pragma unroll
    for (int i = 0; i < 4; ++i){
      int m = m0 + 16*i + ln;
      af[i] = *(const half8*)&As[m*128 + (kb ^ ((m&7)<<3))];
    }
    #pragma unroll
    for (int j = 0; j < 4; ++j){
      int nn = wc + 16*j + ln;
      bf[j] = *(const half8*)&Bs[nn*128 + (kb ^ ((nn&7)<<3))];
    }
    #pragma unroll
    for (int i = 0; i < 4; ++i)
      #pragma unroll
      for (int j = 0; j < 4; ++j)
        acc[i][j] = __builtin_amdgcn_mfma_f32_16x16x32_f16(af[i], bf[j], acc[i][j], 0, 0, 0);
  }

  float b2v[4];
  #pragma unroll
  for (int j = 0; j < 4; ++j) b2v[j] = b2[wc + 16*j + ln];
  float ps[4], pq[4];
  #pragma unroll
  for (int j = 0; j < 4; ++j){ ps[j] = 0.f; pq[j] = 0.f; }
  #pragma unroll
  for (int i = 0; i < 4; ++i){
    #pragma unroll
    for (int r = 0; r < 4; ++r){
      int rg = rbase + m0 + 16*i + 4*q + r;
      if (rg < NN){
        #pragma unroll
        for (int j = 0; j < 4; ++j){
          float v = acc[i][j][r] + b2v[j];
          z2[(size_t)rg*HID + wc + 16*j + ln] = f2h(v);
          ps[j] += v; pq[j] += v*v;
        }
      }
    }
  }
  red[tid] = 0.f;
  if (tid < 128) red[128 + tid] = 0.f;
  __syncthreads();
  #pragma unroll
  for (int j = 0; j < 4; ++j){
    int c = wc + 16*j + ln;
    atomicAdd(&red[c], ps[j]);
    atomicAdd(&red[128 + c], pq[j]);
  }
  __syncthreads();
  if (tid < 128){
    atomicAdd(&bnS[tid], red[tid]);
    atomicAdd(&bnQ[tid], red[128 + tid]);
  }
}

// ======================= fused pool + head (last-layer BN applied inline from z2) =======================
__global__ __launch_bounds__(192) void kPoolHead(const ushort_t* __restrict__ z2,
    const float* __restrict__ bnS, const float* __restrict__ bnQ,
    const float* __restrict__ gamma, const float* __restrict__ beta,
    const int* __restrict__ bid, const int* __restrict__ tidx,
    const float* __restrict__ temb,
    const float* __restrict__ w1, const float* __restrict__ b1,
    const float* __restrict__ w2, const float* __restrict__ b2,
    const float* __restrict__ w3, const float* __restrict__ b3,
    float* __restrict__ out){
  __shared__ float gv[192];
  __shared__ float t1[128];
  __shared__ float t2[64];
  int b = blockIdx.x, t = threadIdx.x;
  int lo = 0, hi = NN;
  while (lo < hi){ int m = (lo + hi) >> 1; if (bid[m] < b) lo = m + 1; else hi = m; }
  int s = lo;
  lo = 0; hi = NN;
  while (lo < hi){ int m = (lo + hi) >> 1; if (bid[m] < b + 1) lo = m + 1; else hi = m; }
  int e = lo;
  if (t < HID){
    float mean = bnS[t] * (1.f/NN);
    float var  = bnQ[t] * (1.f/NN) - mean*mean;
    float scl  = rsqrtf(var + 1e-5f) * gamma[t];
    float sft  = beta[t] - mean*scl;
    float acc = 0.f;
    for (int n = s; n < e; ++n)
      acc += fmaxf(fmaf(h2f(z2[(size_t)n*HID + t]), scl, sft), 0.f);
    gv[t] = acc;
  } else {
    gv[t] = temb[tidx[b]*TE + (t - HID)];
  }
  __syncthreads();
  float acc = b1[t & 127];
  if (t < HID){
    for (int k = 0; k < 192; ++k) acc = fmaf(gv[k], w1[k*HID + t], acc);
    t1[t] = fmaxf(acc, 0.f);
  }
  __syncthreads();
  if (t < 64){
    float a2 = b2[t];
    for (int k = 0; k < 128; ++k) a2 = fmaf(t1[k], w2[k*64 + t], a2);
    t2[t] = fmaxf(a2, 0.f);
  }
  __syncthreads();
  if (t == 0){
    float sv = b3[0];
    for (int k = 0; k < 64; ++k) sv = fmaf(t2[k], w3[k], sv);
    out[b] = sv;
  }
}

// ======================= launch =======================
extern "C" void kernel_launch(void* const* d_in, const int* in_sizes, int n_in,
                              void* d_out, int out_size, void* d_ws, size_t ws_size,
                              hipStream_t stream){
  const float* x     = (const float*)d_in[0];
  const int*   ei    = (const int*)  d_in[1];
  const float* eattr = (const float*)d_in[2];
  const int*   bids  = (const int*)  d_in[3];
  const int*   tgt   = (const int*)  d_in[4];
  const float* nw    = (const float*)d_in[5];
  const float* nb    = (const float*)d_in[6];
  const float* eps   = (const float*)d_in[7];
  const float* ew    = (const float*)d_in[8];
  const float* eb    = (const float*)d_in[9];
  const float* w1    = (const float*)d_in[10];
  const float* bb1   = (const float*)d_in[11];
  const float* w2    = (const float*)d_in[12];
  const float* bb2   = (const float*)d_in[13];
  const float* gam   = (const float*)d_in[14];
  const float* bet   = (const float*)d_in[15];
  const float* temb  = (const float*)d_in[16];
  const float* h1w   = (const float*)d_in[17];
  const float* h1b   = (const float*)d_in[18];
  const float* h2w   = (const float*)d_in[19];
  const float* h2b   = (const float*)d_in[20];
  const float* h3w   = (const float*)d_in[21];
  const float* h3b   = (const float*)d_in[22];
  float* out = (float*)d_out;

  ushort_t* ab   = (ushort_t*)d_ws;                     // (NN+128)*128
  ushort_t* wtb  = ab + (size_t)(NN + 128)*HID;         // 6*16384
  ushort_t* wemb2= wtb + (size_t)6*16384;               // NIN*HID
  ushort_t* hf   = wemb2 + (size_t)NIN*HID;             // (NN+64)*128
  ushort_t* z2   = hf + (size_t)(NN + 64)*HID;          // NN*128 (f16)
  unsigned* eaPos = (unsigned*)(z2 + (size_t)NN*HID);   // NE*8
  float* bnS = (float*)(eaPos + (size_t)NE*8);          // NL*128
  float* bnQ = bnS + NL*HID;                            // NL*128
  int* offs  = (int*)(bnQ + NL*HID);                    // NN+1
  int* cnt   = offs + NN + 1;                           // NN
  int* curs  = cnt + NN;                                // NN
  int* perm  = curs + NN;                               // NE
  int* srcPos= perm + NE;                               // NE
  int* psum  = srcPos + NE;                             // 256
  int* pofs  = psum + 256;                              // 256

  const int* esrc = ei;
  const int* edst = ei + NE;

  kConvW      <<<(6*16384 + NIN*HID + 2*NL*HID + NN + 255)/256, 256, 0, stream>>>(w1, w2, nw, wtb, wemb2, bnS, cnt);
  kHist       <<<(NE + 255)/256, 256, 0, stream>>>(edst, cnt);
  kPartSum    <<<SCAN_B, 256, 0, stream>>>(cnt, psum);
  kScanPart   <<<1, 256, 0, stream>>>(psum, pofs, offs);
  kScanApply  <<<SCAN_B, 256, 0, stream>>>(cnt, pofs, offs, curs);
  kScatterPerm<<<(NE + 255)/256, 256, 0, stream>>>(edst, curs, perm);
  kGatherEA   <<<(NE + 255)/256, 256, 0, stream>>>(perm, esrc, eattr, srcPos, eaPos);
  kNodeInit2  <<<NN/16, 256, 0, stream>>>(x, wemb2, nb, hf);

  for (int l = 0; l < NL; ++l){
    if (l == 0){
      kAgg<false><<<NB_AGG, 256, 0, stream>>>(hf, eaPos, srcPos, offs,
                                   ew, eb, eps, 0,
                                   bnS, bnQ, gam, bet, ab);
    } else {
      kAgg<true><<<NB_AGG, 256, 0, stream>>>(z2, eaPos, srcPos, offs,
                                   ew + (size_t)l*EIN*HID, eb + (size_t)l*HID, eps, l,
                                   bnS + (size_t)(l-1)*HID, bnQ + (size_t)(l-1)*HID,
                                   gam + (size_t)(l-1)*HID, bet + (size_t)(l-1)*HID, ab);
    }
    kMlp<<<(NN + BM2 - 1)/BM2, 256, 0, stream>>>(ab, z2,
                                 wtb + (size_t)l*16384, bb1 + (size_t)l*HID,
                                 wtb + (size_t)(3+l)*16384, bb2 + (size_t)l*HID,
                                 bnS + (size_t)l*HID, bnQ + (size_t)l*HID);
  }

  kPoolHead<<<NG, 192, 0, stream>>>(z2, bnS + (size_t)(NL-1)*HID, bnQ + (size_t)(NL-1)*HID,
                                    gam + (size_t)(NL-1)*HID, bet + (size_t)(NL-1)*HID,
                                    bids, tgt, temb,
                                    h1w, h1b, h2w, h2b, h3w, h3b, out);
}